// Round 6
// baseline (1026.337 us; speedup 1.0000x reference)
//
#include <hip/hip_runtime.h>
#include <stdint.h>

#define B_    8192
#define IN_   1024
#define HID_  2048
#define UP_   2048
#define H_    8
#define HS_   256
#define EPS_  1e-5f

typedef __bf16 bf16x8 __attribute__((ext_vector_type(8)));
typedef float f32x4 __attribute__((ext_vector_type(4)));
typedef unsigned short u16x4 __attribute__((ext_vector_type(4)));
typedef unsigned short u16x8 __attribute__((ext_vector_type(8)));

__device__ __forceinline__ unsigned short f2bf(float f) {
  union { float f; unsigned int u; } v; v.f = f;
  unsigned int u = v.u;
  unsigned int r = (u + 0x7fffu + ((u >> 16) & 1u)) >> 16;  // RNE
  return (unsigned short)r;
}
__device__ __forceinline__ float bf2f(unsigned short h) {
  union { unsigned int u; float f; } v; v.u = ((unsigned int)h) << 16;
  return v.f;
}

// global->LDS direct load, 16B per lane (guide §5; m97/m201 pattern).
__device__ __forceinline__ void gload_lds16(const void* g, void* l) {
  auto gp = reinterpret_cast<const uint32_t __attribute__((address_space(1)))*>(
      reinterpret_cast<uintptr_t>(g));
  auto lp = reinterpret_cast<uint32_t __attribute__((address_space(3)))*>(
      reinterpret_cast<uintptr_t>(l));
  __builtin_amdgcn_global_load_lds(gp, lp, 16, 0, 0);
}

// A-fragment prefetch (4 ds_read_b128) into a named ping-pong set (rule #20).
#define PREFETCH_AF(DST, BASE, MI0)                                         \
  DST[0][0] = *(const bf16x8*)((BASE) + (aRdBase + (MI0) * 2048));          \
  DST[0][1] = *(const bf16x8*)((BASE) + ((aRdBase + (MI0) * 2048) ^ 64));   \
  DST[1][0] = *(const bf16x8*)((BASE) + (aRdBase + ((MI0) + 1) * 2048));    \
  DST[1][1] = *(const bf16x8*)((BASE) + ((aRdBase + ((MI0) + 1) * 2048) ^ 64));

#define MFMA_CLUSTER(AF, Q)                                                 \
  _Pragma("unroll")                                                         \
  for (int kq = 0; kq < 2; ++kq)                                            \
    _Pragma("unroll")                                                       \
    for (int m2 = 0; m2 < 2; ++m2)                                          \
      _Pragma("unroll")                                                     \
      for (int ni = 0; ni < 4; ++ni)                                        \
        acc[(Q) * 2 + m2][ni] = __builtin_amdgcn_mfma_f32_16x16x32_bf16(    \
            AF[m2][kq], bfr[ni][kq], acc[(Q) * 2 + m2][ni], 0, 0, 0);

// ---------------------------------------------------------------------------
// 256x256 8-phase bf16 GEMM with register-fragment pipelining (round 6).
// C[m][col] = (sum_k A[m][k] * W[col][k] + bias[col]) * scale  [+ ADD]
// Split epilogue: col0 < c_split -> C/bias/scale, else C2/bias2/scale2.
// BM=BN=256, BK=64, 8 waves (2M x 4N), per-wave 128x64, acc[8][4] f32x4.
// LDS 160 KiB: A tri-buffer (T%3)*32K; B double-buffer at +96K + (T&1)*32K.
// KEY (r6): A-frag ds_reads for phase q+1 issue AFTER phase q's lgkmcnt(0),
// so their LDS drain overlaps q's 16-MFMA cluster (ds_read||MFMA interleave,
// guide m196/m201 lever). B-frags (8 reads) blocking at q0 only.
// vmcnt(6) moved BEFORE q3's barrier: retires exactly tile T+1 (audited:
// outstanding at that point = B(T+1)h1 + Tq0,q1,q2 issues = 8 -> wait 6).
// Tail (T+2>=NT): vmcnt(0). XOR slot swizzle via pre-swizzled global source.
// ---------------------------------------------------------------------------
template <typename OutT, bool HAS_ADD>
__global__ __launch_bounds__(512, 2) void gemm8p(
    const unsigned short* __restrict__ A, int lda, int a_zoff,
    const unsigned short* __restrict__ W, int ldw, int w_zoff,
    const float* __restrict__ bias, const float* __restrict__ bias2,
    int bias_zoff,
    OutT* __restrict__ C, OutT* __restrict__ C2, int ldc, int c_zoff,
    int c_split,
    const float* __restrict__ ADD, float scale, float scale2, int K)
{
  __shared__ char lds[163840];
  const int z = blockIdx.z;
  A += (size_t)z * a_zoff;
  W += (size_t)z * w_zoff;
  if (bias) bias += (size_t)z * bias_zoff;
  if (bias2) bias2 += (size_t)z * bias_zoff;

  // T1: bijective XCD swizzle (m204 formula) on the flat per-z tile id.
  const int nwg = gridDim.x * gridDim.y;
  const int orig = blockIdx.y * gridDim.x + blockIdx.x;
  const int q8 = nwg >> 3, r8 = nwg & 7;
  const int xcd = orig & 7, xi = orig >> 3;
  const int wg = (xcd < r8 ? xcd * (q8 + 1) : r8 * (q8 + 1) + (xcd - r8) * q8) + xi;
  const int bx = wg % gridDim.x, by = wg / gridDim.x;

  const int t = threadIdx.x;
  const int lane = t & 63, wave = t >> 6;     // 8 waves
  const int wr = wave >> 2, wc = wave & 3;    // 2 x 4
  const int l15 = lane & 15, l4 = lane >> 4;
  const int row0 = by * 256, col0 = bx * 256;

  // staging per-lane invariants (pre-swizzled source slot)
  const int lrow = lane >> 3;                  // 0..7
  const int lslot = (lane & 7) ^ lrow;         // involution per row parity
  const size_t aLane = (size_t)lrow * lda * 2 + (size_t)lslot * 16;
  const size_t wLane = (size_t)lrow * ldw * 2 + (size_t)lslot * 16;
  const char* Abase = (const char*)A;
  const char* Wbase = (const char*)W;

  // ds_read per-lane base byte offsets within a tile (kq=0); kq=1 is ^64
  const int aRdBase = (wr * 128 + l15) * 128 + (((l4) ^ (l15 & 7)) * 16);
  const int bRdBase = (wc * 64 + l15) * 128 + (((l4) ^ (l15 & 7)) * 16);

  auto issueA = [&](int abuf, int half, int tile) {
#pragma unroll
    for (int j = 0; j < 2; ++j) {
      const int rbase = half * 128 + j * 64 + wave * 8;
      gload_lds16(Abase + (size_t)(row0 + rbase) * (lda * 2) + (size_t)tile * 128 + aLane,
                  lds + abuf * 32768 + rbase * 128 + lane * 16);
    }
  };
  auto issueB = [&](int bbuf, int half, int tile) {
#pragma unroll
    for (int j = 0; j < 2; ++j) {
      const int rbase = half * 128 + j * 64 + wave * 8;
      gload_lds16(Wbase + (size_t)(col0 + rbase) * (ldw * 2) + (size_t)tile * 128 + wLane,
                  lds + 98304 + bbuf * 32768 + rbase * 128 + lane * 16);
    }
  };

  f32x4 acc[8][4] = {};
  const int NT = K >> 6;

  bf16x8 bfr[4][2];          // B-frags, whole tile
  bf16x8 afA[2][2], afB[2][2];  // A-frag ping-pong (even/odd phase)

  // prologue: tile0 + tile1 staged; retire tile0; prefetch afA for T0q0.
  issueA(0, 0, 0); issueA(0, 1, 0);
  issueB(0, 0, 0); issueB(0, 1, 0);
  if (NT > 1) {
    issueA(1, 0, 1); issueA(1, 1, 1);
    issueB(1, 0, 1); issueB(1, 1, 1);
    asm volatile("s_waitcnt vmcnt(8)" ::: "memory");   // tile0 resident
  } else {
    asm volatile("s_waitcnt vmcnt(0)" ::: "memory");
  }
  __builtin_amdgcn_s_barrier();
  __builtin_amdgcn_sched_barrier(0);
  {
    const char* ldsA0 = lds;
    PREFETCH_AF(afA, ldsA0, 0)
  }

  for (int T = 0; T < NT; ++T) {
    const char* ldsA = lds + (T % 3) * 32768;
    const char* ldsAn = lds + ((T + 1) % 3) * 32768;
    const char* ldsB = lds + 98304 + (T & 1) * 32768;
    const int abufN = (T + 2) % 3;
    const int bbufN = T & 1;
#pragma unroll
    for (int q = 0; q < 4; ++q) {
      // ---- pre-barrier window: counted vmcnt (q3) + gload staging ----
      if (q == 3) {
        if (T + 2 < NT) asm volatile("s_waitcnt vmcnt(6)" ::: "memory");
        else            asm volatile("s_waitcnt vmcnt(0)" ::: "memory");
      }
      if (q == 0 && T + 2 < NT) issueA(abufN, 0, T + 2);
      if (q == 1 && T + 2 < NT) issueA(abufN, 1, T + 2);
      if (q == 2 && T + 2 < NT) issueB(bbufN, 0, T + 2);
      if (q == 3 && T + 2 < NT) issueB(bbufN, 1, T + 2);
      __builtin_amdgcn_s_barrier();
      // ---- B-frags for this tile (blocking, q0 only) ----
      if (q == 0) {
#pragma unroll
        for (int ni = 0; ni < 4; ++ni) {
          bfr[ni][0] = *(const bf16x8*)(ldsB + (bRdBase + ni * 2048));
          bfr[ni][1] = *(const bf16x8*)(ldsB + ((bRdBase + ni * 2048) ^ 64));
        }
      }
      asm volatile("s_waitcnt lgkmcnt(0)" ::: "memory");
      __builtin_amdgcn_sched_barrier(0);   // rule #18: pin MFMA below the wait
      // ---- prefetch NEXT phase's A-frags: drain overlaps this MFMA ----
      if (q == 0) { PREFETCH_AF(afB, ldsA, 2) }
      else if (q == 1) { PREFETCH_AF(afA, ldsA, 4) }
      else if (q == 2) { PREFETCH_AF(afB, ldsA, 6) }
      else if (T + 1 < NT) { PREFETCH_AF(afA, ldsAn, 0) }  // q3 -> T+1 q0
      __builtin_amdgcn_s_setprio(1);
      if ((q & 1) == 0) { MFMA_CLUSTER(afA, q) }
      else              { MFMA_CLUSTER(afB, q) }
      __builtin_amdgcn_s_setprio(0);
      __builtin_amdgcn_s_barrier();
      __builtin_amdgcn_sched_barrier(0);
    }
  }

  // epilogue: C/D layout col=lane&15, row=(lane>>4)*4+reg (guide §3)
  const float* bp = bias;
  OutT* Cp = C;
  int cbase = col0;
  float sc = scale;
  if (col0 >= c_split) { bp = bias2; Cp = C2; cbase = col0 - c_split; sc = scale2; }
#pragma unroll
  for (int mi = 0; mi < 8; ++mi) {
#pragma unroll
    for (int ni = 0; ni < 4; ++ni) {
#pragma unroll
      for (int r = 0; r < 4; ++r) {
        const int m = row0 + wr * 128 + mi * 16 + l4 * 4 + r;
        const int n = wc * 64 + ni * 16 + l15;
        float v = acc[mi][ni][r];
        if (bp) v += bp[cbase + n];
        v *= sc;
        const size_t ci = (size_t)m * ldc + (size_t)z * c_zoff + cbase + n;
        if constexpr (HAS_ADD) v += ADD[ci];
        if constexpr (sizeof(OutT) == 2) Cp[ci] = (OutT)f2bf(v);
        else Cp[ci] = v;
      }
    }
  }
}

// ---------------------------------------------------------------------------
// denom[m] = max_n | sum_z part[z][m][n] |   (split-K reduction), one block/row
// ---------------------------------------------------------------------------
__global__ __launch_bounds__(256) void denom_reduce(
    const float* __restrict__ part, float* __restrict__ denom)
{
  const int m = blockIdx.x, t = threadIdx.x;
  const size_t P = (size_t)HID_ * HID_;
  float v = 0.f;
  for (int n = t; n < HID_; n += 256) {
    const size_t o = (size_t)m * HID_ + n;
    float s = part[o] + part[P + o] + part[2 * P + o] + part[3 * P + o];
    v = fmaxf(v, fabsf(s));
  }
#pragma unroll
  for (int off = 1; off < 64; off <<= 1) v = fmaxf(v, __shfl_xor(v, off, 64));
  __shared__ float red[4];
  if ((t & 63) == 0) red[t >> 6] = v;
  __syncthreads();
  if (t == 0) denom[m] = fmaxf(fmaxf(red[0], red[1]), fmaxf(red[2], red[3]));
}

// ---------------------------------------------------------------------------
// down split-K reduce: out = part0 + part1 + bias + x
// ---------------------------------------------------------------------------
__global__ __launch_bounds__(256) void down_reduce(
    const float* __restrict__ part, const float* __restrict__ x,
    const float* __restrict__ bias, float* __restrict__ out)
{
  const size_t idx = ((size_t)blockIdx.x * 256 + threadIdx.x) * 4;
  const size_t P = (size_t)B_ * IN_;
  f32x4 a = *(const f32x4*)(part + idx);
  f32x4 b = *(const f32x4*)(part + P + idx);
  f32x4 xv = *(const f32x4*)(x + idx);
  const int j = (int)(idx & (IN_ - 1));
  f32x4 bv = *(const f32x4*)(bias + j);
  f32x4 o;
#pragma unroll
  for (int e = 0; e < 4; ++e) o[e] = a[e] + b[e] + bv[e] + xv[e];
  *(f32x4*)(out + idx) = o;
}

// ---------------------------------------------------------------------------
// Transposing bf16 converter: in [R][C] (f32 or bf16) -> out [C][R] bf16.
// grid (C/32, R/32, Z), block (32,8). Separate in/out z strides.
// ---------------------------------------------------------------------------
template <typename InT>
__global__ __launch_bounds__(256) void transpose_bf(
    const InT* __restrict__ in, unsigned short* __restrict__ out, int R, int C,
    int izoff, int ozoff)
{
  __shared__ float tile[32][33];
  in += (size_t)blockIdx.z * izoff;
  out += (size_t)blockIdx.z * ozoff;
  const int cb = blockIdx.x * 32, rb = blockIdx.y * 32;
  const int tx = threadIdx.x, ty = threadIdx.y;
  for (int i = ty; i < 32; i += 8) {
    InT v = in[(size_t)(rb + i) * C + cb + tx];
    float f;
    if constexpr (sizeof(InT) == 2) f = bf2f((unsigned short)v);
    else f = (float)v;
    tile[i][tx] = f;
  }
  __syncthreads();
  for (int i = ty; i < 32; i += 8)
    out[(size_t)(cb + i) * R + rb + tx] = f2bf(tile[tx][i]);
}

// ---------------------------------------------------------------------------
// LayerNorm over 1024 features, one block per row, write bf16.
// ---------------------------------------------------------------------------
__global__ __launch_bounds__(256) void ln_kernel(
    const float* __restrict__ x, const float* __restrict__ g,
    const float* __restrict__ b, unsigned short* __restrict__ xn)
{
  const int brow = blockIdx.x, t = threadIdx.x;
  const int lane = t & 63, wave = t >> 6;
  const float* xr = x + (size_t)brow * IN_;
  f32x4 v = *(const f32x4*)(xr + t * 4);
  float s = v[0] + v[1] + v[2] + v[3];
  float q = v[0]*v[0] + v[1]*v[1] + v[2]*v[2] + v[3]*v[3];
#pragma unroll
  for (int off = 32; off; off >>= 1) {
    s += __shfl_xor(s, off, 64);
    q += __shfl_xor(q, off, 64);
  }
  __shared__ float ss[4], sq[4];
  if (lane == 0) { ss[wave] = s; sq[wave] = q; }
  __syncthreads();
  s = ss[0] + ss[1] + ss[2] + ss[3];
  q = sq[0] + sq[1] + sq[2] + sq[3];
  const float mean = s * (1.f / IN_);
  const float var = q * (1.f / IN_) - mean * mean;
  const float rs = rsqrtf(var + EPS_);
  u16x4 o;
#pragma unroll
  for (int e = 0; e < 4; ++e) {
    const int j = t * 4 + e;
    o[e] = f2bf((v[e] - mean) * rs * g[j] + b[j]);
  }
  *(u16x4*)(xn + (size_t)brow * IN_ + t * 4) = o;
}

// ---------------------------------------------------------------------------
// Causal conv1d (k=4, left pad 3) along features + SiLU. One block per row.
// ---------------------------------------------------------------------------
__global__ __launch_bounds__(256) void conv_kernel(
    const unsigned short* __restrict__ xul, const float* __restrict__ cw,
    const float* __restrict__ cb, unsigned short* __restrict__ xc)
{
  const int brow = blockIdx.x, t = threadIdx.x;
  const size_t base = (size_t)brow * UP_;
  const int j0 = t * 8;
  float xv[11];
#pragma unroll
  for (int e = 0; e < 11; ++e) {
    const int j = j0 + e - 3;
    xv[e] = (j >= 0) ? bf2f(xul[base + j]) : 0.f;
  }
  const float w0 = cw[0], w1 = cw[1], w2 = cw[2], w3 = cw[3], bb = cb[0];
  u16x8 o;
#pragma unroll
  for (int e = 0; e < 8; ++e) {
    float sv = bb + w0 * xv[e] + w1 * xv[e + 1] + w2 * xv[e + 2] + w3 * xv[e + 3];
    o[e] = f2bf(sv / (1.f + expf(-sv)));
  }
  *(u16x8*)(xc + base + j0) = o;
}

// ---------------------------------------------------------------------------
// Gates, 64x64 tile per block: m_t,c_t,n_t fp32 + nT bf16 (LDS transpose).
// i/f read as bf16 from the merged sif buffer [B][6144] (i at +2048, f +4096).
// ---------------------------------------------------------------------------
__global__ __launch_bounds__(256) void gates_kernel(
    const unsigned short* __restrict__ sif,
    const unsigned short* __restrict__ kb, const unsigned short* __restrict__ vb,
    const float* __restrict__ mprev, const float* __restrict__ cprev,
    const float* __restrict__ nprev,
    float* __restrict__ mo, float* __restrict__ co, float* __restrict__ no,
    unsigned short* __restrict__ nT)
{
  __shared__ unsigned short nt_t[64][72];
  const int t = threadIdx.x;
  const int r = t >> 2, cq = t & 3;
  const int row = blockIdx.y * 64 + r;
  const int colb = blockIdx.x * 64 + cq * 16;
  const size_t hidb = (size_t)row * HID_ + colb;
  const size_t sifb = (size_t)row * 6144 + colb;
#pragma unroll
  for (int e4 = 0; e4 < 4; ++e4) {
    const int c4 = e4 * 4;
    f32x4 mp = *(const f32x4*)(mprev + hidb + c4);
    f32x4 cp = *(const f32x4*)(cprev + hidb + c4);
    f32x4 np = *(const f32x4*)(nprev + hidb + c4);
    u16x4 iv = *(const u16x4*)(sif + sifb + 2048 + c4);
    u16x4 fv = *(const u16x4*)(sif + sifb + 4096 + c4);
    u16x4 kv = *(const u16x4*)(kb + hidb + c4);
    u16x4 vv = *(const u16x4*)(vb + hidb + c4);
    f32x4 mo4, co4, no4;
#pragma unroll
    for (int e = 0; e < 4; ++e) {
      const float ft = bf2f(fv[e]) + mp[e];
      const float it = bf2f(iv[e]);
      const float mt = fmaxf(ft, it);
      const float ie = expf(it - mt);
      const float fe = expf(ft - mt);
      const float k = bf2f(kv[e]), v = bf2f(vv[e]);
      mo4[e] = mt;
      co4[e] = fe * cp[e] + ie * (v * k);
      no4[e] = fe * np[e] + ie * k;
      nt_t[r][cq * 16 + c4 + e] = f2bf(no4[e]);
    }
    *(f32x4*)(mo + hidb + c4) = mo4;
    *(f32x4*)(co + hidb + c4) = co4;
    *(f32x4*)(no + hidb + c4) = no4;
  }
  __syncthreads();
  // transposed write: nT[col][row]
  const int cT = t >> 2, sq = t & 3;
  u16x8 o0, o1;
#pragma unroll
  for (int e = 0; e < 8; ++e) {
    o0[e] = nt_t[sq * 16 + e][cT];
    o1[e] = nt_t[sq * 16 + 8 + e][cT];
  }
  const size_t ob = (size_t)(blockIdx.x * 64 + cT) * B_ + blockIdx.y * 64 + sq * 16;
  *(u16x8*)(nT + ob) = o0;
  *(u16x8*)(nT + ob + 8) = o1;
}

// ---------------------------------------------------------------------------
// h_t = o*c_t*q/denom; GroupNorm (8 groups of 256); pre = (hn+skip)*silu(xur).
// skip read from merged sif buffer (row stride 6144, cols 0..2047).
// ---------------------------------------------------------------------------
__global__ __launch_bounds__(256) void hgn_kernel(
    const float* __restrict__ ct, const unsigned short* __restrict__ olin,
    const unsigned short* __restrict__ qb, const float* __restrict__ denom,
    const unsigned short* __restrict__ sif, const unsigned short* __restrict__ xurb,
    const float* __restrict__ gng, const float* __restrict__ gnb,
    float* __restrict__ ho, unsigned short* __restrict__ pre)
{
  const int brow = blockIdx.x, t = threadIdx.x;
  const size_t base = (size_t)brow * HID_ + t * 8;
  u16x8 ov = *(const u16x8*)(olin + base);
  u16x8 qv = *(const u16x8*)(qb + base);
  f32x4 c0 = *(const f32x4*)(ct + base);
  f32x4 c1 = *(const f32x4*)(ct + base + 4);
  float h[8];
  float s = 0.f, sq = 0.f;
#pragma unroll
  for (int e = 0; e < 8; ++e) {
    const float o = 1.f / (1.f + expf(-bf2f(ov[e])));
    const float cv = (e < 4) ? c0[e] : c1[e - 4];
    const float hv = o * cv * bf2f(qv[e]) / denom[t * 8 + e];
    h[e] = hv; s += hv; sq += hv * hv;
  }
#pragma unroll
  for (int e = 0; e < 8; ++e) ho[base + e] = h[e];
#pragma unroll
  for (int off = 1; off < 32; off <<= 1) {
    s += __shfl_xor(s, off, 64);
    sq += __shfl_xor(sq, off, 64);
  }
  const float mean = s * (1.f / HS_);
  const float var = sq * (1.f / HS_) - mean * mean;
  const float rs = rsqrtf(var + EPS_);
  u16x8 sv = *(const u16x8*)(sif + (size_t)brow * 6144 + t * 8);
  u16x8 xv = *(const u16x8*)(xurb + base);
  u16x8 pv;
#pragma unroll
  for (int e = 0; e < 8; ++e) {
    const int j = t * 8 + e;
    const float hn = (h[e] - mean) * rs * gng[j] + gnb[j];
    const float xr = bf2f(xv[e]);
    const float sil = xr / (1.f + expf(-xr));
    pv[e] = f2bf((hn + bf2f(sv[e])) * sil);
  }
  *(u16x8*)(pre + base) = pv;
}

// ---------------------------------------------------------------------------
extern "C" void kernel_launch(void* const* d_in, const int* in_sizes, int n_in,
                              void* d_out, int out_size, void* d_ws, size_t ws_size,
                              hipStream_t stream)
{
  const float* x      = (const float*)d_in[0];
  const float* c_prev = (const float*)d_in[2];
  const float* n_prev = (const float*)d_in[3];
  const float* m_prev = (const float*)d_in[4];
  const float* ln_g   = (const float*)d_in[5];
  const float* ln_b   = (const float*)d_in[6];
  const float* w_ul   = (const float*)d_in[7];
  const float* b_ul   = (const float*)d_in[8];
  const float* w_ur   = (const float*)d_in[9];
  const float* b_ur   = (const float*)d_in[10];
  const float* conv_w = (const float*)d_in[11];
  const float* conv_b = (const float*)d_in[12];
  const float* w_skip = (const float*)d_in[13];
  const float* b_skip = (const float*)d_in[14];
  const float* w_q    = (const float*)d_in[15];
  const float* b_q    = (const float*)d_in[16];
  const float* w_k    = (const float*)d_in[17];
  const float* b_k    = (const float*)d_in[18];
  const float* w_v    = (const float*)d_in[19];
  const float* b_v    = (const float*)d_in[20];
  const float* w_i    = (const float*)d_in[21];
  const float* b_i    = (const float*)d_in[22];
  const float* w_f    = (const float*)d_in[23];
  const float* b_f    = (const float*)d_in[24];
  const float* w_o    = (const float*)d_in[25];
  const float* b_o    = (const float*)d_in[26];
  const float* gn_g   = (const float*)d_in[27];
  const float* gn_b   = (const float*)d_in[28];
  const float* w_down = (const float*)d_in[29];
  const float* b_down = (const float*)d_in[30];

  float* out_p = (float*)d_out;                       // [B, IN]
  float* h_p = out_p + (size_t)B_ * IN_;              // [B, HID]
  float* c_p = h_p + (size_t)B_ * HID_;
  float* n_p = c_p + (size_t)B_ * HID_;
  float* m_p = n_p + (size_t)B_ * HID_;

  char* ws = (char*)d_ws;
  size_t off = 0;
  auto alloc = [&](size_t n) -> void* {
    void* p = ws + off;
    off += (n + 255) & ~(size_t)255;
    return p;
  };

  const size_t BH2 = (size_t)B_ * HID_ * 2;

  unsigned short* xn_bf   = (unsigned short*)alloc((size_t)B_ * IN_ * 2);
  unsigned short* xul_bf  = (unsigned short*)alloc(BH2);
  unsigned short* xur_bf  = (unsigned short*)alloc(BH2);
  unsigned short* xc_bf   = (unsigned short*)alloc(BH2);
  unsigned short* sif_bf  = (unsigned short*)alloc((size_t)B_ * 6144 * 2);
  unsigned short* q_bf    = (unsigned short*)alloc(BH2);
  unsigned short* k_bf    = (unsigned short*)alloc(BH2);
  unsigned short* v_bf    = (unsigned short*)alloc(BH2);
  unsigned short* olin_bf = (unsigned short*)alloc(BH2);
  unsigned short* qT_bf   = (unsigned short*)alloc(BH2);
  unsigned short* nT_bf   = (unsigned short*)alloc(BH2);
  unsigned short* pre_bf  = (unsigned short*)alloc(BH2);
  float* denom = (float*)alloc(HID_ * sizeof(float));
  float* part  = (float*)alloc((size_t)4 * HID_ * HID_ * sizeof(float));
  float* b_sif = (float*)alloc(6144 * sizeof(float));
  unsigned short* wt_ulur = (unsigned short*)alloc((size_t)4096 * IN_ * 2);
  unsigned short* wt_sif  = (unsigned short*)alloc((size_t)6144 * UP_ * 2);
  unsigned short* wt_qk   = (unsigned short*)alloc((size_t)H_ * 512 * HS_ * 2);
  unsigned short* wt_v    = (unsigned short*)alloc((size_t)H_ * HS_ * HS_ * 2);
  unsigned short* wt_o    = (unsigned short*)alloc((size_t)UP_ * HID_ * 2);
  unsigned short* wt_down = (unsigned short*)alloc((size_t)HID_ * IN_ * 2);

  if (off > ws_size) return;  // fail loudly (poisoned output) rather than OOB

  const dim3 tb32(32, 8);
  const int NOSPLIT = 1 << 30;

  // ---- stacked biases (d2d async copies, graph-capture safe) ----
  hipMemcpyAsync(b_sif, b_skip, 2048 * 4, hipMemcpyDeviceToDevice, stream);
  hipMemcpyAsync(b_sif + 2048, b_i, 2048 * 4, hipMemcpyDeviceToDevice, stream);
  hipMemcpyAsync(b_sif + 4096, b_f, 2048 * 4, hipMemcpyDeviceToDevice, stream);

  // ---- weight convert+transpose to bf16 [N][K] (stacked) ----
  transpose_bf<float><<<dim3(64, 32, 1), tb32, 0, stream>>>(w_ul, wt_ulur, 1024, 2048, 0, 0);
  transpose_bf<float><<<dim3(64, 32, 1), tb32, 0, stream>>>(w_ur, wt_ulur + (size_t)2048 * 1024, 1024, 2048, 0, 0);
  transpose_bf<float><<<dim3(64, 64, 1), tb32, 0, stream>>>(w_skip, wt_sif, 2048, 2048, 0, 0);
  transpose_bf<float><<<dim3(64, 64, 1), tb32, 0, stream>>>(w_i, wt_sif + (size_t)2048 * 2048, 2048, 2048, 0, 0);
  transpose_bf<float><<<dim3(64, 64, 1), tb32, 0, stream>>>(w_f, wt_sif + (size_t)4096 * 2048, 2048, 2048, 0, 0);
  transpose_bf<float><<<dim3(8, 8, 8), tb32, 0, stream>>>(w_q, wt_qk, 256, 256, 65536, 131072);
  transpose_bf<float><<<dim3(8, 8, 8), tb32, 0, stream>>>(w_k, wt_qk + 65536, 256, 256, 65536, 131072);
  transpose_bf<float><<<dim3(8, 8, 8), tb32, 0, stream>>>(w_v, wt_v, 256, 256, 65536, 65536);
  transpose_bf<float><<<dim3(64, 64, 1), tb32, 0, stream>>>(w_o, wt_o, 2048, 2048, 0, 0);
  transpose_bf<float><<<dim3(32, 64, 1), tb32, 0, stream>>>(w_down, wt_down, 2048, 1024, 0, 0);

  // ---- LayerNorm ----
  ln_kernel<<<B_, 256, 0, stream>>>(x, ln_g, ln_b, xn_bf);

  // ---- merged up projections: [xul | xur] = xn @ [w_ul | w_ur] ----
  gemm8p<unsigned short, false><<<dim3(16, 32, 1), 512, 0, stream>>>(
      xn_bf, IN_, 0, wt_ulur, IN_, 0, b_ul, b_ur, 0,
      xul_bf, xur_bf, HID_, 0, 2048, nullptr, 1.f, 1.f, IN_);

  // ---- conv4 + silu ----
  conv_kernel<<<B_, 256, 0, stream>>>(xul_bf, conv_w, conv_b, xc_bf);

  // ---- merged skip|i|f from xc ----
  gemm8p<unsigned short, false><<<dim3(24, 32, 1), 512, 0, stream>>>(
      xc_bf, UP_, 0, wt_sif, UP_, 0, b_sif, nullptr, 0,
      sif_bf, sif_bf, 6144, 0, NOSPLIT, nullptr, 1.f, 1.f, UP_);

  // ---- merged q|k (blockdiag, per-head z), k scaled by 1/16 ----
  gemm8p<unsigned short, false><<<dim3(2, 32, 8), 512, 0, stream>>>(
      xc_bf, UP_, HS_, wt_qk, HS_, 512 * HS_, b_q, b_k, HS_,
      q_bf, k_bf, HID_, HS_, 256, nullptr, 1.f, 0.0625f, HS_);

  // ---- v (blockdiag from xul) ----
  gemm8p<unsigned short, false><<<dim3(1, 32, 8), 512, 0, stream>>>(
      xul_bf, UP_, HS_, wt_v, HS_, HS_ * HS_, b_v, nullptr, HS_,
      v_bf, v_bf, HID_, HS_, NOSPLIT, nullptr, 1.f, 1.f, HS_);

  // ---- o-gate linear from xul ----
  gemm8p<unsigned short, false><<<dim3(8, 32, 1), 512, 0, stream>>>(
      xul_bf, UP_, 0, wt_o, UP_, 0, b_o, nullptr, 0,
      olin_bf, olin_bf, HID_, 0, NOSPLIT, nullptr, 1.f, 1.f, UP_);

  // ---- gates -> m_t, c_t, n_t (fp32 to d_out) + nT bf16 ----
  gates_kernel<<<dim3(HID_ / 64, B_ / 64, 1), 256, 0, stream>>>(
      sif_bf, k_bf, v_bf, m_prev, c_prev, n_prev, m_p, c_p, n_p, nT_bf);

  // ---- q transpose for denom GEMM ----
  transpose_bf<unsigned short><<<dim3(64, 256, 1), tb32, 0, stream>>>(
      q_bf, qT_bf, B_, HID_, 0, 0);

  // ---- denom: split-K x4 partial GEMMs, then reduce ----
  gemm8p<float, false><<<dim3(8, 8, 4), 512, 0, stream>>>(
      nT_bf, B_, B_ / 4, qT_bf, B_, B_ / 4, nullptr, nullptr, 0,
      part, part, HID_, HID_ * HID_, NOSPLIT, nullptr, 1.f, 1.f, B_ / 4);
  denom_reduce<<<HID_, 256, 0, stream>>>(part, denom);

  // ---- h_t, GroupNorm, fuse with skip & silu(xur) ----
  hgn_kernel<<<B_, 256, 0, stream>>>(
      c_p, olin_bf, q_bf, denom, sif_bf, xur_bf, gn_g, gn_b, h_p, pre_bf);

  // ---- down projection: split-K x2 partials, then reduce(+bias+residual) ----
  gemm8p<float, false><<<dim3(4, 32, 2), 512, 0, stream>>>(
      pre_bf, UP_, 1024, wt_down, UP_, 1024, nullptr, nullptr, 0,
      part, part, IN_, B_ * IN_, NOSPLIT, nullptr, 1.f, 1.f, 1024);
  down_reduce<<<(B_ * IN_ / 4) / 256, 256, 0, stream>>>(part, x, b_down, out_p);
}

// Round 7
// 992.798 us; speedup vs baseline: 1.0338x; 1.0338x over previous
//
#include <hip/hip_runtime.h>
#include <stdint.h>

#define B_    8192
#define IN_   1024
#define HID_  2048
#define UP_   2048
#define H_    8
#define HS_   256
#define EPS_  1e-5f

typedef __bf16 bf16x8 __attribute__((ext_vector_type(8)));
typedef float f32x4 __attribute__((ext_vector_type(4)));
typedef unsigned short u16x4 __attribute__((ext_vector_type(4)));
typedef unsigned short u16x8 __attribute__((ext_vector_type(8)));

__device__ __forceinline__ unsigned short f2bf(float f) {
  union { float f; unsigned int u; } v; v.f = f;
  unsigned int u = v.u;
  unsigned int r = (u + 0x7fffu + ((u >> 16) & 1u)) >> 16;  // RNE
  return (unsigned short)r;
}
__device__ __forceinline__ float bf2f(unsigned short h) {
  union { unsigned int u; float f; } v; v.u = ((unsigned int)h) << 16;
  return v.f;
}

// global->LDS direct load, 16B per lane (guide §5; m97/m201 pattern).
__device__ __forceinline__ void gload_lds16(const void* g, void* l) {
  auto gp = reinterpret_cast<const uint32_t __attribute__((address_space(1)))*>(
      reinterpret_cast<uintptr_t>(g));
  auto lp = reinterpret_cast<uint32_t __attribute__((address_space(3)))*>(
      reinterpret_cast<uintptr_t>(l));
  __builtin_amdgcn_global_load_lds(gp, lp, 16, 0, 0);
}

#define SB0 __builtin_amdgcn_sched_barrier(0)

// A-fragment load (4 ds_read_b128) into a named register set (rule #20).
#define PREFETCH_AF(DST, BASE, MI0)                                         \
  DST[0][0] = *(const bf16x8*)((BASE) + (aRdBase + (MI0) * 2048));          \
  DST[0][1] = *(const bf16x8*)((BASE) + ((aRdBase + (MI0) * 2048) ^ 64));   \
  DST[1][0] = *(const bf16x8*)((BASE) + (aRdBase + ((MI0) + 1) * 2048));    \
  DST[1][1] = *(const bf16x8*)((BASE) + ((aRdBase + ((MI0) + 1) * 2048) ^ 64));

#define LOAD_BFR(BASE)                                                      \
  _Pragma("unroll")                                                         \
  for (int ni = 0; ni < 4; ++ni) {                                          \
    bfr[ni][0] = *(const bf16x8*)((BASE) + (bRdBase + ni * 2048));          \
    bfr[ni][1] = *(const bf16x8*)((BASE) + ((bRdBase + ni * 2048) ^ 64));   \
  }

#define MFMA_CLUSTER(AF, Q)                                                 \
  __builtin_amdgcn_s_setprio(1);                                           \
  _Pragma("unroll")                                                         \
  for (int kq = 0; kq < 2; ++kq)                                            \
    _Pragma("unroll")                                                       \
    for (int m2 = 0; m2 < 2; ++m2)                                          \
      _Pragma("unroll")                                                     \
      for (int ni = 0; ni < 4; ++ni)                                        \
        acc[(Q) * 2 + m2][ni] = __builtin_amdgcn_mfma_f32_16x16x32_bf16(    \
            AF[m2][kq], bfr[ni][kq], acc[(Q) * 2 + m2][ni], 0, 0, 0);       \
  __builtin_amdgcn_s_setprio(0);

// ---------------------------------------------------------------------------
// 256x256 bf16 GEMM, coarse-barrier tile schedule (round 7).
// C[m][col] = (sum_k A[m][k] * W[col][k] + bias[col]) * scale  [+ ADD]
// Split epilogue: col0 < c_split -> C/bias/scale, else C2/bias2/scale2.
// BM=BN=256, BK=64, 8 waves (2M x 4N), per-wave 128x64, acc[8][4] f32x4.
// LDS 160 KiB: A tri-buffer (T%3)*32K; B dual-buffer at +96K + (T&1)*32K.
// Schedule per tile (2 barriers, counted lgkm inside, AITER-style):
//   entry: bfr=B(T), afA=A(T)q0, afB=A(T)q1 pre-issued (16 lgkm outstanding)
//   lgkm(4) [B+afA done] -> MFMA q0 ; read afA<-q2, gload A(T+2)h0
//   lgkm(4) [afB done]   -> MFMA q1 ; MID-BARRIER (all B(T) reads complete)
//   read afB<-q3, gload A(T+2)h1 + B(T+2)h0,h1   (B-buf write safe post-mid-bar)
//   lgkm(4) [q2 done]    -> MFMA q2
//   lgkm(0) [q3 done]    -> MFMA q3
//   vmcnt(8|0) [tile T+1 resident] ; pre-issue T+1 frags ; TILE BARRIER
// Buffer-hazard audit: A(T+2)->(T+2)%3, last read tile T-1, all reads done
// before tile-T barrier (issue is post-barrier). B(T+2)->(T&1): reads of B(T)
// complete per-wave before each wave's MFMA q0, hence before mid-barrier;
// gloads issue post-mid-barrier. Pre-issued T+1 frag reads target buffers
// retired by the vmcnt and not rewritten until after next mid-barrier.
// ---------------------------------------------------------------------------
template <typename OutT, bool HAS_ADD>
__global__ __launch_bounds__(512, 2) void gemm8p(
    const unsigned short* __restrict__ A, int lda, int a_zoff,
    const unsigned short* __restrict__ W, int ldw, int w_zoff,
    const float* __restrict__ bias, const float* __restrict__ bias2,
    int bias_zoff,
    OutT* __restrict__ C, OutT* __restrict__ C2, int ldc, int c_zoff,
    int c_split,
    const float* __restrict__ ADD, float scale, float scale2, int K)
{
  __shared__ char lds[163840];
  const int z = blockIdx.z;
  A += (size_t)z * a_zoff;
  W += (size_t)z * w_zoff;
  if (bias) bias += (size_t)z * bias_zoff;
  if (bias2) bias2 += (size_t)z * bias_zoff;

  // T1: bijective XCD swizzle (m204 formula) on the flat per-z tile id.
  const int nwg = gridDim.x * gridDim.y;
  const int orig = blockIdx.y * gridDim.x + blockIdx.x;
  const int q8 = nwg >> 3, r8 = nwg & 7;
  const int xcd = orig & 7, xi = orig >> 3;
  const int wg = (xcd < r8 ? xcd * (q8 + 1) : r8 * (q8 + 1) + (xcd - r8) * q8) + xi;
  const int bx = wg % gridDim.x, by = wg / gridDim.x;

  const int t = threadIdx.x;
  const int lane = t & 63, wave = t >> 6;     // 8 waves
  const int wr = wave >> 2, wc = wave & 3;    // 2 x 4
  const int l15 = lane & 15, l4 = lane >> 4;
  const int row0 = by * 256, col0 = bx * 256;

  // staging per-lane invariants (pre-swizzled source slot)
  const int lrow = lane >> 3;                  // 0..7
  const int lslot = (lane & 7) ^ lrow;         // involution per row parity
  const size_t aLane = (size_t)lrow * lda * 2 + (size_t)lslot * 16;
  const size_t wLane = (size_t)lrow * ldw * 2 + (size_t)lslot * 16;
  const char* Abase = (const char*)A;
  const char* Wbase = (const char*)W;

  // ds_read per-lane base byte offsets within a tile (kq=0); kq=1 is ^64
  const int aRdBase = (wr * 128 + l15) * 128 + (((l4) ^ (l15 & 7)) * 16);
  const int bRdBase = (wc * 64 + l15) * 128 + (((l4) ^ (l15 & 7)) * 16);

  auto issueA = [&](int abuf, int half, int tile) {
#pragma unroll
    for (int j = 0; j < 2; ++j) {
      const int rbase = half * 128 + j * 64 + wave * 8;
      gload_lds16(Abase + (size_t)(row0 + rbase) * (lda * 2) + (size_t)tile * 128 + aLane,
                  lds + abuf * 32768 + rbase * 128 + lane * 16);
    }
  };
  auto issueB = [&](int bbuf, int half, int tile) {
#pragma unroll
    for (int j = 0; j < 2; ++j) {
      const int rbase = half * 128 + j * 64 + wave * 8;
      gload_lds16(Wbase + (size_t)(col0 + rbase) * (ldw * 2) + (size_t)tile * 128 + wLane,
                  lds + 98304 + bbuf * 32768 + rbase * 128 + lane * 16);
    }
  };

  f32x4 acc[8][4] = {};
  const int NT = K >> 6;

  bf16x8 bfr[4][2];             // B-frags for current tile (8 b128)
  bf16x8 afA[2][2], afB[2][2];  // A-frag ping-pong (4+4 b128)

  // ---- prologue: stage tile0+tile1; retire tile0; pre-issue T0 frags ----
  issueA(0, 0, 0); issueA(0, 1, 0);
  issueB(0, 0, 0); issueB(0, 1, 0);
  if (NT > 1) {
    issueA(1, 0, 1); issueA(1, 1, 1);
    issueB(1, 0, 1); issueB(1, 1, 1);
    asm volatile("s_waitcnt vmcnt(8)" ::: "memory");   // tile0 resident
  } else {
    asm volatile("s_waitcnt vmcnt(0)" ::: "memory");
  }
  SB0;
  {
    const char* a0 = lds;
    const char* b0 = lds + 98304;
    LOAD_BFR(b0)
    PREFETCH_AF(afA, a0, 0)
    PREFETCH_AF(afB, a0, 2)
  }
  __builtin_amdgcn_s_barrier();
  SB0;

  for (int T = 0; T < NT; ++T) {
    const char* ldsA = lds + (T % 3) * 32768;
    const int abufN = (T + 2) % 3;
    const int bbufN = T & 1;                   // == (T+2)&1
    // q0: B + afA done (16 outstanding -> 4: afB pending)
    asm volatile("s_waitcnt lgkmcnt(4)" ::: "memory"); SB0;
    MFMA_CLUSTER(afA, 0)
    PREFETCH_AF(afA, ldsA, 4)                  // q2 frags (drain under q1)
    if (T + 2 < NT) issueA(abufN, 0, T + 2);
    // q1: afB done (8 outstanding -> 4: q2 pending)
    asm volatile("s_waitcnt lgkmcnt(4)" ::: "memory"); SB0;
    MFMA_CLUSTER(afB, 1)
    __builtin_amdgcn_s_barrier();              // mid-tile: B(T) reads complete
    SB0;
    PREFETCH_AF(afB, ldsA, 6)                  // q3 frags (drain under q2)
    if (T + 2 < NT) {
      issueA(abufN, 1, T + 2);
      issueB(bbufN, 0, T + 2);                 // safe: post-mid-barrier
      issueB(bbufN, 1, T + 2);
    }
    // q2: q2 frags done (8 outstanding -> 4: q3 pending)
    asm volatile("s_waitcnt lgkmcnt(4)" ::: "memory"); SB0;
    MFMA_CLUSTER(afA, 2)
    asm volatile("s_waitcnt lgkmcnt(0)" ::: "memory"); SB0;
    MFMA_CLUSTER(afB, 3)
    // tile boundary: tile T+1 resident (retire its 8 loads; keep T+2 in flight)
    if (T + 2 < NT) asm volatile("s_waitcnt vmcnt(8)" ::: "memory");
    else            asm volatile("s_waitcnt vmcnt(0)" ::: "memory");
    SB0;
    if (T + 1 < NT) {                          // pre-issue T+1 frags
      const char* aN = lds + ((T + 1) % 3) * 32768;
      const char* bN = lds + 98304 + ((T + 1) & 1) * 32768;
      LOAD_BFR(bN)
      PREFETCH_AF(afA, aN, 0)
      PREFETCH_AF(afB, aN, 2)
    }
    __builtin_amdgcn_s_barrier();
    SB0;
  }

  // epilogue: C/D layout col=lane&15, row=(lane>>4)*4+reg (guide §3)
  const float* bp = bias;
  OutT* Cp = C;
  int cbase = col0;
  float sc = scale;
  if (col0 >= c_split) { bp = bias2; Cp = C2; cbase = col0 - c_split; sc = scale2; }
#pragma unroll
  for (int mi = 0; mi < 8; ++mi) {
#pragma unroll
    for (int ni = 0; ni < 4; ++ni) {
#pragma unroll
      for (int r = 0; r < 4; ++r) {
        const int m = row0 + wr * 128 + mi * 16 + l4 * 4 + r;
        const int n = wc * 64 + ni * 16 + l15;
        float v = acc[mi][ni][r];
        if (bp) v += bp[cbase + n];
        v *= sc;
        const size_t ci = (size_t)m * ldc + (size_t)z * c_zoff + cbase + n;
        if constexpr (HAS_ADD) v += ADD[ci];
        if constexpr (sizeof(OutT) == 2) Cp[ci] = (OutT)f2bf(v);
        else Cp[ci] = v;
      }
    }
  }
}

// ---------------------------------------------------------------------------
// denom[m] = max_n | sum_z part[z][m][n] |   (split-K reduction), one block/row
// ---------------------------------------------------------------------------
__global__ __launch_bounds__(256) void denom_reduce(
    const float* __restrict__ part, float* __restrict__ denom)
{
  const int m = blockIdx.x, t = threadIdx.x;
  const size_t P = (size_t)HID_ * HID_;
  float v = 0.f;
  for (int n = t; n < HID_; n += 256) {
    const size_t o = (size_t)m * HID_ + n;
    float s = part[o] + part[P + o] + part[2 * P + o] + part[3 * P + o];
    v = fmaxf(v, fabsf(s));
  }
#pragma unroll
  for (int off = 1; off < 64; off <<= 1) v = fmaxf(v, __shfl_xor(v, off, 64));
  __shared__ float red[4];
  if ((t & 63) == 0) red[t >> 6] = v;
  __syncthreads();
  if (t == 0) denom[m] = fmaxf(fmaxf(red[0], red[1]), fmaxf(red[2], red[3]));
}

// ---------------------------------------------------------------------------
// down split-K reduce: out = part0 + part1 + bias + x
// ---------------------------------------------------------------------------
__global__ __launch_bounds__(256) void down_reduce(
    const float* __restrict__ part, const float* __restrict__ x,
    const float* __restrict__ bias, float* __restrict__ out)
{
  const size_t idx = ((size_t)blockIdx.x * 256 + threadIdx.x) * 4;
  const size_t P = (size_t)B_ * IN_;
  f32x4 a = *(const f32x4*)(part + idx);
  f32x4 b = *(const f32x4*)(part + P + idx);
  f32x4 xv = *(const f32x4*)(x + idx);
  const int j = (int)(idx & (IN_ - 1));
  f32x4 bv = *(const f32x4*)(bias + j);
  f32x4 o;
#pragma unroll
  for (int e = 0; e < 4; ++e) o[e] = a[e] + b[e] + bv[e] + xv[e];
  *(f32x4*)(out + idx) = o;
}

// ---------------------------------------------------------------------------
// Transposing bf16 converter: in [R][C] (f32 or bf16) -> out [C][R] bf16.
// grid (C/32, R/32, Z), block (32,8). Separate in/out z strides.
// ---------------------------------------------------------------------------
template <typename InT>
__global__ __launch_bounds__(256) void transpose_bf(
    const InT* __restrict__ in, unsigned short* __restrict__ out, int R, int C,
    int izoff, int ozoff)
{
  __shared__ float tile[32][33];
  in += (size_t)blockIdx.z * izoff;
  out += (size_t)blockIdx.z * ozoff;
  const int cb = blockIdx.x * 32, rb = blockIdx.y * 32;
  const int tx = threadIdx.x, ty = threadIdx.y;
  for (int i = ty; i < 32; i += 8) {
    InT v = in[(size_t)(rb + i) * C + cb + tx];
    float f;
    if constexpr (sizeof(InT) == 2) f = bf2f((unsigned short)v);
    else f = (float)v;
    tile[i][tx] = f;
  }
  __syncthreads();
  for (int i = ty; i < 32; i += 8)
    out[(size_t)(cb + i) * R + rb + tx] = f2bf(tile[tx][i]);
}

// ---------------------------------------------------------------------------
// LayerNorm over 1024 features, one block per row, write bf16.
// ---------------------------------------------------------------------------
__global__ __launch_bounds__(256) void ln_kernel(
    const float* __restrict__ x, const float* __restrict__ g,
    const float* __restrict__ b, unsigned short* __restrict__ xn)
{
  const int brow = blockIdx.x, t = threadIdx.x;
  const int lane = t & 63, wave = t >> 6;
  const float* xr = x + (size_t)brow * IN_;
  f32x4 v = *(const f32x4*)(xr + t * 4);
  float s = v[0] + v[1] + v[2] + v[3];
  float q = v[0]*v[0] + v[1]*v[1] + v[2]*v[2] + v[3]*v[3];
#pragma unroll
  for (int off = 32; off; off >>= 1) {
    s += __shfl_xor(s, off, 64);
    q += __shfl_xor(q, off, 64);
  }
  __shared__ float ss[4], sq[4];
  if (lane == 0) { ss[wave] = s; sq[wave] = q; }
  __syncthreads();
  s = ss[0] + ss[1] + ss[2] + ss[3];
  q = sq[0] + sq[1] + sq[2] + sq[3];
  const float mean = s * (1.f / IN_);
  const float var = q * (1.f / IN_) - mean * mean;
  const float rs = rsqrtf(var + EPS_);
  u16x4 o;
#pragma unroll
  for (int e = 0; e < 4; ++e) {
    const int j = t * 4 + e;
    o[e] = f2bf((v[e] - mean) * rs * g[j] + b[j]);
  }
  *(u16x4*)(xn + (size_t)brow * IN_ + t * 4) = o;
}

// ---------------------------------------------------------------------------
// Causal conv1d (k=4, left pad 3) along features + SiLU. One block per row.
// ---------------------------------------------------------------------------
__global__ __launch_bounds__(256) void conv_kernel(
    const unsigned short* __restrict__ xul, const float* __restrict__ cw,
    const float* __restrict__ cb, unsigned short* __restrict__ xc)
{
  const int brow = blockIdx.x, t = threadIdx.x;
  const size_t base = (size_t)brow * UP_;
  const int j0 = t * 8;
  float xv[11];
#pragma unroll
  for (int e = 0; e < 11; ++e) {
    const int j = j0 + e - 3;
    xv[e] = (j >= 0) ? bf2f(xul[base + j]) : 0.f;
  }
  const float w0 = cw[0], w1 = cw[1], w2 = cw[2], w3 = cw[3], bb = cb[0];
  u16x8 o;
#pragma unroll
  for (int e = 0; e < 8; ++e) {
    float sv = bb + w0 * xv[e] + w1 * xv[e + 1] + w2 * xv[e + 2] + w3 * xv[e + 3];
    o[e] = f2bf(sv / (1.f + expf(-sv)));
  }
  *(u16x8*)(xc + base + j0) = o;
}

// ---------------------------------------------------------------------------
// Gates, 64x64 tile per block: m_t,c_t,n_t fp32 + nT bf16 (LDS transpose).
// i/f read as bf16 from the merged sif buffer [B][6144] (i at +2048, f +4096).
// ---------------------------------------------------------------------------
__global__ __launch_bounds__(256) void gates_kernel(
    const unsigned short* __restrict__ sif,
    const unsigned short* __restrict__ kb, const unsigned short* __restrict__ vb,
    const float* __restrict__ mprev, const float* __restrict__ cprev,
    const float* __restrict__ nprev,
    float* __restrict__ mo, float* __restrict__ co, float* __restrict__ no,
    unsigned short* __restrict__ nT)
{
  __shared__ unsigned short nt_t[64][72];
  const int t = threadIdx.x;
  const int r = t >> 2, cq = t & 3;
  const int row = blockIdx.y * 64 + r;
  const int colb = blockIdx.x * 64 + cq * 16;
  const size_t hidb = (size_t)row * HID_ + colb;
  const size_t sifb = (size_t)row * 6144 + colb;
#pragma unroll
  for (int e4 = 0; e4 < 4; ++e4) {
    const int c4 = e4 * 4;
    f32x4 mp = *(const f32x4*)(mprev + hidb + c4);
    f32x4 cp = *(const f32x4*)(cprev + hidb + c4);
    f32x4 np = *(const f32x4*)(nprev + hidb + c4);
    u16x4 iv = *(const u16x4*)(sif + sifb + 2048 + c4);
    u16x4 fv = *(const u16x4*)(sif + sifb + 4096 + c4);
    u16x4 kv = *(const u16x4*)(kb + hidb + c4);
    u16x4 vv = *(const u16x4*)(vb + hidb + c4);
    f32x4 mo4, co4, no4;
#pragma unroll
    for (int e = 0; e < 4; ++e) {
      const float ft = bf2f(fv[e]) + mp[e];
      const float it = bf2f(iv[e]);
      const float mt = fmaxf(ft, it);
      const float ie = expf(it - mt);
      const float fe = expf(ft - mt);
      const float k = bf2f(kv[e]), v = bf2f(vv[e]);
      mo4[e] = mt;
      co4[e] = fe * cp[e] + ie * (v * k);
      no4[e] = fe * np[e] + ie * k;
      nt_t[r][cq * 16 + c4 + e] = f2bf(no4[e]);
    }
    *(f32x4*)(mo + hidb + c4) = mo4;
    *(f32x4*)(co + hidb + c4) = co4;
    *(f32x4*)(no + hidb + c4) = no4;
  }
  __syncthreads();
  // transposed write: nT[col][row]
  const int cT = t >> 2, sq = t & 3;
  u16x8 o0, o1;
#pragma unroll
  for (int e = 0; e < 8; ++e) {
    o0[e] = nt_t[sq * 16 + e][cT];
    o1[e] = nt_t[sq * 16 + 8 + e][cT];
  }
  const size_t ob = (size_t)(blockIdx.x * 64 + cT) * B_ + blockIdx.y * 64 + sq * 16;
  *(u16x8*)(nT + ob) = o0;
  *(u16x8*)(nT + ob + 8) = o1;
}

// ---------------------------------------------------------------------------
// h_t = o*c_t*q/denom; GroupNorm (8 groups of 256); pre = (hn+skip)*silu(xur).
// skip read from merged sif buffer (row stride 6144, cols 0..2047).
// ---------------------------------------------------------------------------
__global__ __launch_bounds__(256) void hgn_kernel(
    const float* __restrict__ ct, const unsigned short* __restrict__ olin,
    const unsigned short* __restrict__ qb, const float* __restrict__ denom,
    const unsigned short* __restrict__ sif, const unsigned short* __restrict__ xurb,
    const float* __restrict__ gng, const float* __restrict__ gnb,
    float* __restrict__ ho, unsigned short* __restrict__ pre)
{
  const int brow = blockIdx.x, t = threadIdx.x;
  const size_t base = (size_t)brow * HID_ + t * 8;
  u16x8 ov = *(const u16x8*)(olin + base);
  u16x8 qv = *(const u16x8*)(qb + base);
  f32x4 c0 = *(const f32x4*)(ct + base);
  f32x4 c1 = *(const f32x4*)(ct + base + 4);
  float h[8];
  float s = 0.f, sq = 0.f;
#pragma unroll
  for (int e = 0; e < 8; ++e) {
    const float o = 1.f / (1.f + expf(-bf2f(ov[e])));
    const float cv = (e < 4) ? c0[e] : c1[e - 4];
    const float hv = o * cv * bf2f(qv[e]) / denom[t * 8 + e];
    h[e] = hv; s += hv; sq += hv * hv;
  }
#pragma unroll
  for (int e = 0; e < 8; ++e) ho[base + e] = h[e];
#pragma unroll
  for (int off = 1; off < 32; off <<= 1) {
    s += __shfl_xor(s, off, 64);
    sq += __shfl_xor(sq, off, 64);
  }
  const float mean = s * (1.f / HS_);
  const float var = sq * (1.f / HS_) - mean * mean;
  const float rs = rsqrtf(var + EPS_);
  u16x8 sv = *(const u16x8*)(sif + (size_t)brow * 6144 + t * 8);
  u16x8 xv = *(const u16x8*)(xurb + base);
  u16x8 pv;
#pragma unroll
  for (int e = 0; e < 8; ++e) {
    const int j = t * 8 + e;
    const float hn = (h[e] - mean) * rs * gng[j] + gnb[j];
    const float xr = bf2f(xv[e]);
    const float sil = xr / (1.f + expf(-xr));
    pv[e] = f2bf((hn + bf2f(sv[e])) * sil);
  }
  *(u16x8*)(pre + base) = pv;
}

// ---------------------------------------------------------------------------
extern "C" void kernel_launch(void* const* d_in, const int* in_sizes, int n_in,
                              void* d_out, int out_size, void* d_ws, size_t ws_size,
                              hipStream_t stream)
{
  const float* x      = (const float*)d_in[0];
  const float* c_prev = (const float*)d_in[2];
  const float* n_prev = (const float*)d_in[3];
  const float* m_prev = (const float*)d_in[4];
  const float* ln_g   = (const float*)d_in[5];
  const float* ln_b   = (const float*)d_in[6];
  const float* w_ul   = (const float*)d_in[7];
  const float* b_ul   = (const float*)d_in[8];
  const float* w_ur   = (const float*)d_in[9];
  const float* b_ur   = (const float*)d_in[10];
  const float* conv_w = (const float*)d_in[11];
  const float* conv_b = (const float*)d_in[12];
  const float* w_skip = (const float*)d_in[13];
  const float* b_skip = (const float*)d_in[14];
  const float* w_q    = (const float*)d_in[15];
  const float* b_q    = (const float*)d_in[16];
  const float* w_k    = (const float*)d_in[17];
  const float* b_k    = (const float*)d_in[18];
  const float* w_v    = (const float*)d_in[19];
  const float* b_v    = (const float*)d_in[20];
  const float* w_i    = (const float*)d_in[21];
  const float* b_i    = (const float*)d_in[22];
  const float* w_f    = (const float*)d_in[23];
  const float* b_f    = (const float*)d_in[24];
  const float* w_o    = (const float*)d_in[25];
  const float* b_o    = (const float*)d_in[26];
  const float* gn_g   = (const float*)d_in[27];
  const float* gn_b   = (const float*)d_in[28];
  const float* w_down = (const float*)d_in[29];
  const float* b_down = (const float*)d_in[30];

  float* out_p = (float*)d_out;                       // [B, IN]
  float* h_p = out_p + (size_t)B_ * IN_;              // [B, HID]
  float* c_p = h_p + (size_t)B_ * HID_;
  float* n_p = c_p + (size_t)B_ * HID_;
  float* m_p = n_p + (size_t)B_ * HID_;

  char* ws = (char*)d_ws;
  size_t off = 0;
  auto alloc = [&](size_t n) -> void* {
    void* p = ws + off;
    off += (n + 255) & ~(size_t)255;
    return p;
  };

  const size_t BH2 = (size_t)B_ * HID_ * 2;

  unsigned short* xn_bf   = (unsigned short*)alloc((size_t)B_ * IN_ * 2);
  unsigned short* xul_bf  = (unsigned short*)alloc(BH2);
  unsigned short* xur_bf  = (unsigned short*)alloc(BH2);
  unsigned short* xc_bf   = (unsigned short*)alloc(BH2);
  unsigned short* sif_bf  = (unsigned short*)alloc((size_t)B_ * 6144 * 2);
  unsigned short* q_bf    = (unsigned short*)alloc(BH2);
  unsigned short* k_bf    = (unsigned short*)alloc(BH2);
  unsigned short* v_bf    = (unsigned short*)alloc(BH2);
  unsigned short* olin_bf = (unsigned short*)alloc(BH2);
  unsigned short* qT_bf   = (unsigned short*)alloc(BH2);
  unsigned short* nT_bf   = (unsigned short*)alloc(BH2);
  unsigned short* pre_bf  = (unsigned short*)alloc(BH2);
  float* denom = (float*)alloc(HID_ * sizeof(float));
  float* part  = (float*)alloc((size_t)4 * HID_ * HID_ * sizeof(float));
  float* b_sif = (float*)alloc(6144 * sizeof(float));
  unsigned short* wt_ulur = (unsigned short*)alloc((size_t)4096 * IN_ * 2);
  unsigned short* wt_sif  = (unsigned short*)alloc((size_t)6144 * UP_ * 2);
  unsigned short* wt_qk   = (unsigned short*)alloc((size_t)H_ * 512 * HS_ * 2);
  unsigned short* wt_v    = (unsigned short*)alloc((size_t)H_ * HS_ * HS_ * 2);
  unsigned short* wt_o    = (unsigned short*)alloc((size_t)UP_ * HID_ * 2);
  unsigned short* wt_down = (unsigned short*)alloc((size_t)HID_ * IN_ * 2);

  if (off > ws_size) return;  // fail loudly (poisoned output) rather than OOB

  const dim3 tb32(32, 8);
  const int NOSPLIT = 1 << 30;

  // ---- stacked biases (d2d async copies, graph-capture safe) ----
  hipMemcpyAsync(b_sif, b_skip, 2048 * 4, hipMemcpyDeviceToDevice, stream);
  hipMemcpyAsync(b_sif + 2048, b_i, 2048 * 4, hipMemcpyDeviceToDevice, stream);
  hipMemcpyAsync(b_sif + 4096, b_f, 2048 * 4, hipMemcpyDeviceToDevice, stream);

  // ---- weight convert+transpose to bf16 [N][K] (stacked) ----
  transpose_bf<float><<<dim3(64, 32, 1), tb32, 0, stream>>>(w_ul, wt_ulur, 1024, 2048, 0, 0);
  transpose_bf<float><<<dim3(64, 32, 1), tb32, 0, stream>>>(w_ur, wt_ulur + (size_t)2048 * 1024, 1024, 2048, 0, 0);
  transpose_bf<float><<<dim3(64, 64, 1), tb32, 0, stream>>>(w_skip, wt_sif, 2048, 2048, 0, 0);
  transpose_bf<float><<<dim3(64, 64, 1), tb32, 0, stream>>>(w_i, wt_sif + (size_t)2048 * 2048, 2048, 2048, 0, 0);
  transpose_bf<float><<<dim3(64, 64, 1), tb32, 0, stream>>>(w_f, wt_sif + (size_t)4096 * 2048, 2048, 2048, 0, 0);
  transpose_bf<float><<<dim3(8, 8, 8), tb32, 0, stream>>>(w_q, wt_qk, 256, 256, 65536, 131072);
  transpose_bf<float><<<dim3(8, 8, 8), tb32, 0, stream>>>(w_k, wt_qk + 65536, 256, 256, 65536, 131072);
  transpose_bf<float><<<dim3(8, 8, 8), tb32, 0, stream>>>(w_v, wt_v, 256, 256, 65536, 65536);
  transpose_bf<float><<<dim3(64, 64, 1), tb32, 0, stream>>>(w_o, wt_o, 2048, 2048, 0, 0);
  transpose_bf<float><<<dim3(32, 64, 1), tb32, 0, stream>>>(w_down, wt_down, 2048, 1024, 0, 0);

  // ---- LayerNorm ----
  ln_kernel<<<B_, 256, 0, stream>>>(x, ln_g, ln_b, xn_bf);

  // ---- merged up projections: [xul | xur] = xn @ [w_ul | w_ur] ----
  gemm8p<unsigned short, false><<<dim3(16, 32, 1), 512, 0, stream>>>(
      xn_bf, IN_, 0, wt_ulur, IN_, 0, b_ul, b_ur, 0,
      xul_bf, xur_bf, HID_, 0, 2048, nullptr, 1.f, 1.f, IN_);

  // ---- conv4 + silu ----
  conv_kernel<<<B_, 256, 0, stream>>>(xul_bf, conv_w, conv_b, xc_bf);

  // ---- merged skip|i|f from xc ----
  gemm8p<unsigned short, false><<<dim3(24, 32, 1), 512, 0, stream>>>(
      xc_bf, UP_, 0, wt_sif, UP_, 0, b_sif, nullptr, 0,
      sif_bf, sif_bf, 6144, 0, NOSPLIT, nullptr, 1.f, 1.f, UP_);

  // ---- merged q|k (blockdiag, per-head z), k scaled by 1/16 ----
  gemm8p<unsigned short, false><<<dim3(2, 32, 8), 512, 0, stream>>>(
      xc_bf, UP_, HS_, wt_qk, HS_, 512 * HS_, b_q, b_k, HS_,
      q_bf, k_bf, HID_, HS_, 256, nullptr, 1.f, 0.0625f, HS_);

  // ---- v (blockdiag from xul) ----
  gemm8p<unsigned short, false><<<dim3(1, 32, 8), 512, 0, stream>>>(
      xul_bf, UP_, HS_, wt_v, HS_, HS_ * HS_, b_v, nullptr, HS_,
      v_bf, v_bf, HID_, HS_, NOSPLIT, nullptr, 1.f, 1.f, HS_);

  // ---- o-gate linear from xul ----
  gemm8p<unsigned short, false><<<dim3(8, 32, 1), 512, 0, stream>>>(
      xul_bf, UP_, 0, wt_o, UP_, 0, b_o, nullptr, 0,
      olin_bf, olin_bf, HID_, 0, NOSPLIT, nullptr, 1.f, 1.f, UP_);

  // ---- gates -> m_t, c_t, n_t (fp32 to d_out) + nT bf16 ----
  gates_kernel<<<dim3(HID_ / 64, B_ / 64, 1), 256, 0, stream>>>(
      sif_bf, k_bf, v_bf, m_prev, c_prev, n_prev, m_p, c_p, n_p, nT_bf);

  // ---- q transpose for denom GEMM ----
  transpose_bf<unsigned short><<<dim3(64, 256, 1), tb32, 0, stream>>>(
      q_bf, qT_bf, B_, HID_, 0, 0);

  // ---- denom: split-K x4 partial GEMMs, then reduce ----
  gemm8p<float, false><<<dim3(8, 8, 4), 512, 0, stream>>>(
      nT_bf, B_, B_ / 4, qT_bf, B_, B_ / 4, nullptr, nullptr, 0,
      part, part, HID_, HID_ * HID_, NOSPLIT, nullptr, 1.f, 1.f, B_ / 4);
  denom_reduce<<<HID_, 256, 0, stream>>>(part, denom);

  // ---- h_t, GroupNorm, fuse with skip & silu(xur) ----
  hgn_kernel<<<B_, 256, 0, stream>>>(
      c_p, olin_bf, q_bf, denom, sif_bf, xur_bf, gn_g, gn_b, h_p, pre_bf);

  // ---- down projection: split-K x2 partials, then reduce(+bias+residual) ----
  gemm8p<float, false><<<dim3(4, 32, 2), 512, 0, stream>>>(
      pre_bf, UP_, 1024, wt_down, UP_, 1024, nullptr, nullptr, 0,
      part, part, IN_, B_ * IN_, NOSPLIT, nullptr, 1.f, 1.f, 1024);
  down_reduce<<<(B_ * IN_ / 4) / 256, 256, 0, stream>>>(part, x, b_down, out_p);
}

// Round 8
// 975.437 us; speedup vs baseline: 1.0522x; 1.0178x over previous
//
#include <hip/hip_runtime.h>
#include <stdint.h>

#define B_    8192
#define IN_   1024
#define HID_  2048
#define UP_   2048
#define H_    8
#define HS_   256
#define EPS_  1e-5f

typedef __bf16 bf16x8 __attribute__((ext_vector_type(8)));
typedef float f32x4 __attribute__((ext_vector_type(4)));
typedef unsigned short u16x4 __attribute__((ext_vector_type(4)));
typedef unsigned short u16x8 __attribute__((ext_vector_type(8)));

__device__ __forceinline__ unsigned short f2bf(float f) {
  union { float f; unsigned int u; } v; v.f = f;
  unsigned int u = v.u;
  unsigned int r = (u + 0x7fffu + ((u >> 16) & 1u)) >> 16;  // RNE
  return (unsigned short)r;
}
__device__ __forceinline__ float bf2f(unsigned short h) {
  union { unsigned int u; float f; } v; v.u = ((unsigned int)h) << 16;
  return v.f;
}

// global->LDS direct load, 16B per lane (guide §5; m97/m201 pattern).
__device__ __forceinline__ void gload_lds16(const void* g, void* l) {
  auto gp = reinterpret_cast<const uint32_t __attribute__((address_space(1)))*>(
      reinterpret_cast<uintptr_t>(g));
  auto lp = reinterpret_cast<uint32_t __attribute__((address_space(3)))*>(
      reinterpret_cast<uintptr_t>(l));
  __builtin_amdgcn_global_load_lds(gp, lp, 16, 0, 0);
}

#define SB0 __builtin_amdgcn_sched_barrier(0)

// A-fragment load (4 ds_read_b128) into a named register set (rule #20).
#define PREFETCH_AF(DST, BASE, MI0)                                         \
  DST[0][0] = *(const bf16x8*)((BASE) + (aRdBase + (MI0) * 2048));          \
  DST[0][1] = *(const bf16x8*)((BASE) + ((aRdBase + (MI0) * 2048) ^ 64));   \
  DST[1][0] = *(const bf16x8*)((BASE) + (aRdBase + ((MI0) + 1) * 2048));    \
  DST[1][1] = *(const bf16x8*)((BASE) + ((aRdBase + ((MI0) + 1) * 2048) ^ 64));

#define LOAD_BFR(BASE)                                                      \
  _Pragma("unroll")                                                         \
  for (int ni = 0; ni < 4; ++ni) {                                          \
    bfr[ni][0] = *(const bf16x8*)((BASE) + (bRdBase + ni * 2048));          \
    bfr[ni][1] = *(const bf16x8*)((BASE) + ((bRdBase + ni * 2048) ^ 64));   \
  }

#define MFMA_CLUSTER(AF, Q)                                                 \
  __builtin_amdgcn_s_setprio(1);                                           \
  _Pragma("unroll")                                                         \
  for (int kq = 0; kq < 2; ++kq)                                            \
    _Pragma("unroll")                                                       \
    for (int m2 = 0; m2 < 2; ++m2)                                          \
      _Pragma("unroll")                                                     \
      for (int ni = 0; ni < 4; ++ni)                                        \
        acc[(Q) * 2 + m2][ni] = __builtin_amdgcn_mfma_f32_16x16x32_bf16(    \
            AF[m2][kq], bfr[ni][kq], acc[(Q) * 2 + m2][ni], 0, 0, 0);       \
  __builtin_amdgcn_s_setprio(0);

// ---------------------------------------------------------------------------
// 256x256 bf16 GEMM, coarse-barrier tile schedule (r7) + L2 raster (r8).
// C[m][col] = (sum_k A[m][k] * W[col][k] + bias[col]) * scale  [+ ADD]
// Split epilogue: col0 < c_split -> C/bias/scale, else C2/bias2/scale2.
// BM=BN=256, BK=64, 8 waves (2M x 4N), per-wave 128x64, acc[8][4] f32x4.
// LDS 160 KiB: A tri-buffer (T%3)*32K; B dual-buffer at +96K + (T&1)*32K.
// r8: after the XCD swizzle, wg->(bx,by) in 8-tall column-major row-groups:
// 8 consecutive wgs on an XCD share bx (same W panel) -> W L2-miss / 8.
// Schedule per tile (2 barriers, counted lgkm inside) -- see r7 audit.
// ---------------------------------------------------------------------------
template <typename OutT, bool HAS_ADD>
__global__ __launch_bounds__(512, 2) void gemm8p(
    const unsigned short* __restrict__ A, int lda, int a_zoff,
    const unsigned short* __restrict__ W, int ldw, int w_zoff,
    const float* __restrict__ bias, const float* __restrict__ bias2,
    int bias_zoff,
    OutT* __restrict__ C, OutT* __restrict__ C2, int ldc, int c_zoff,
    int c_split,
    const float* __restrict__ ADD, float scale, float scale2, int K)
{
  __shared__ char lds[163840];
  const int z = blockIdx.z;
  A += (size_t)z * a_zoff;
  W += (size_t)z * w_zoff;
  if (bias) bias += (size_t)z * bias_zoff;
  if (bias2) bias2 += (size_t)z * bias_zoff;

  // T1: bijective XCD swizzle (m204 formula) on the flat per-z tile id.
  const int gx = gridDim.x, gy = gridDim.y;
  const int nwg = gx * gy;
  const int orig = blockIdx.y * gx + blockIdx.x;
  const int q8 = nwg >> 3, r8 = nwg & 7;
  const int xcd = orig & 7, xi = orig >> 3;
  const int wg = (xcd < r8 ? xcd * (q8 + 1) : r8 * (q8 + 1) + (xcd - r8) * q8) + xi;
  // r8: 8-tall row-group raster (bijective when 8 | gy, guard otherwise)
  int bx, by;
  if ((gy & 7) == 0) {
    const int per = gx * 8;
    const int g0 = (wg / per) * 8;
    const int rem = wg % per;
    bx = rem >> 3;
    by = g0 + (rem & 7);
  } else {
    bx = wg % gx;
    by = wg / gx;
  }

  const int t = threadIdx.x;
  const int lane = t & 63, wave = t >> 6;     // 8 waves
  const int wr = wave >> 2, wc = wave & 3;    // 2 x 4
  const int l15 = lane & 15, l4 = lane >> 4;
  const int row0 = by * 256, col0 = bx * 256;

  // staging per-lane invariants (pre-swizzled source slot)
  const int lrow = lane >> 3;                  // 0..7
  const int lslot = (lane & 7) ^ lrow;         // involution per row parity
  const size_t aLane = (size_t)lrow * lda * 2 + (size_t)lslot * 16;
  const size_t wLane = (size_t)lrow * ldw * 2 + (size_t)lslot * 16;
  const char* Abase = (const char*)A;
  const char* Wbase = (const char*)W;

  // ds_read per-lane base byte offsets within a tile (kq=0); kq=1 is ^64
  const int aRdBase = (wr * 128 + l15) * 128 + (((l4) ^ (l15 & 7)) * 16);
  const int bRdBase = (wc * 64 + l15) * 128 + (((l4) ^ (l15 & 7)) * 16);

  auto issueA = [&](int abuf, int half, int tile) {
#pragma unroll
    for (int j = 0; j < 2; ++j) {
      const int rbase = half * 128 + j * 64 + wave * 8;
      gload_lds16(Abase + (size_t)(row0 + rbase) * (lda * 2) + (size_t)tile * 128 + aLane,
                  lds + abuf * 32768 + rbase * 128 + lane * 16);
    }
  };
  auto issueB = [&](int bbuf, int half, int tile) {
#pragma unroll
    for (int j = 0; j < 2; ++j) {
      const int rbase = half * 128 + j * 64 + wave * 8;
      gload_lds16(Wbase + (size_t)(col0 + rbase) * (ldw * 2) + (size_t)tile * 128 + wLane,
                  lds + 98304 + bbuf * 32768 + rbase * 128 + lane * 16);
    }
  };

  f32x4 acc[8][4] = {};
  const int NT = K >> 6;

  bf16x8 bfr[4][2];             // B-frags for current tile (8 b128)
  bf16x8 afA[2][2], afB[2][2];  // A-frag ping-pong (4+4 b128)

  // ---- prologue: stage tile0+tile1; retire tile0; pre-issue T0 frags ----
  issueA(0, 0, 0); issueA(0, 1, 0);
  issueB(0, 0, 0); issueB(0, 1, 0);
  if (NT > 1) {
    issueA(1, 0, 1); issueA(1, 1, 1);
    issueB(1, 0, 1); issueB(1, 1, 1);
    asm volatile("s_waitcnt vmcnt(8)" ::: "memory");   // tile0 resident
  } else {
    asm volatile("s_waitcnt vmcnt(0)" ::: "memory");
  }
  SB0;
  {
    const char* a0 = lds;
    const char* b0 = lds + 98304;
    LOAD_BFR(b0)
    PREFETCH_AF(afA, a0, 0)
    PREFETCH_AF(afB, a0, 2)
  }
  __builtin_amdgcn_s_barrier();
  SB0;

  for (int T = 0; T < NT; ++T) {
    const char* ldsA = lds + (T % 3) * 32768;
    const int abufN = (T + 2) % 3;
    const int bbufN = T & 1;                   // == (T+2)&1
    // q0: B + afA done (16 outstanding -> 4: afB pending)
    asm volatile("s_waitcnt lgkmcnt(4)" ::: "memory"); SB0;
    MFMA_CLUSTER(afA, 0)
    PREFETCH_AF(afA, ldsA, 4)                  // q2 frags (drain under q1)
    if (T + 2 < NT) issueA(abufN, 0, T + 2);
    // q1: afB done (8 outstanding -> 4: q2 pending)
    asm volatile("s_waitcnt lgkmcnt(4)" ::: "memory"); SB0;
    MFMA_CLUSTER(afB, 1)
    __builtin_amdgcn_s_barrier();              // mid-tile: B(T) reads complete
    SB0;
    PREFETCH_AF(afB, ldsA, 6)                  // q3 frags (drain under q2)
    if (T + 2 < NT) {
      issueA(abufN, 1, T + 2);
      issueB(bbufN, 0, T + 2);                 // safe: post-mid-barrier
      issueB(bbufN, 1, T + 2);
    }
    // q2: q2 frags done (8 outstanding -> 4: q3 pending)
    asm volatile("s_waitcnt lgkmcnt(4)" ::: "memory"); SB0;
    MFMA_CLUSTER(afA, 2)
    asm volatile("s_waitcnt lgkmcnt(0)" ::: "memory"); SB0;
    MFMA_CLUSTER(afB, 3)
    // tile boundary: tile T+1 resident (retire its 8 loads; keep T+2 in flight)
    if (T + 2 < NT) asm volatile("s_waitcnt vmcnt(8)" ::: "memory");
    else            asm volatile("s_waitcnt vmcnt(0)" ::: "memory");
    SB0;
    if (T + 1 < NT) {                          // pre-issue T+1 frags
      const char* aN = lds + ((T + 1) % 3) * 32768;
      const char* bN = lds + 98304 + ((T + 1) & 1) * 32768;
      LOAD_BFR(bN)
      PREFETCH_AF(afA, aN, 0)
      PREFETCH_AF(afB, aN, 2)
    }
    __builtin_amdgcn_s_barrier();
    SB0;
  }

  // epilogue: C/D layout col=lane&15, row=(lane>>4)*4+reg (guide §3)
  const float* bp = bias;
  OutT* Cp = C;
  int cbase = col0;
  float sc = scale;
  if (col0 >= c_split) { bp = bias2; Cp = C2; cbase = col0 - c_split; sc = scale2; }
#pragma unroll
  for (int mi = 0; mi < 8; ++mi) {
#pragma unroll
    for (int ni = 0; ni < 4; ++ni) {
#pragma unroll
      for (int r = 0; r < 4; ++r) {
        const int m = row0 + wr * 128 + mi * 16 + l4 * 4 + r;
        const int n = wc * 64 + ni * 16 + l15;
        float v = acc[mi][ni][r];
        if (bp) v += bp[cbase + n];
        v *= sc;
        const size_t ci = (size_t)m * ldc + (size_t)z * c_zoff + cbase + n;
        if constexpr (HAS_ADD) v += ADD[ci];
        if constexpr (sizeof(OutT) == 2) Cp[ci] = (OutT)f2bf(v);
        else Cp[ci] = v;
      }
    }
  }
}

// ---------------------------------------------------------------------------
// denom[m] = max_n | sum_z part[z][m][n] |   (split-K reduction), one block/row
// ---------------------------------------------------------------------------
__global__ __launch_bounds__(256) void denom_reduce(
    const float* __restrict__ part, float* __restrict__ denom)
{
  const int m = blockIdx.x, t = threadIdx.x;
  const size_t P = (size_t)HID_ * HID_;
  float v = 0.f;
  for (int n = t; n < HID_; n += 256) {
    const size_t o = (size_t)m * HID_ + n;
    float s = part[o] + part[P + o] + part[2 * P + o] + part[3 * P + o];
    v = fmaxf(v, fabsf(s));
  }
#pragma unroll
  for (int off = 1; off < 64; off <<= 1) v = fmaxf(v, __shfl_xor(v, off, 64));
  __shared__ float red[4];
  if ((t & 63) == 0) red[t >> 6] = v;
  __syncthreads();
  if (t == 0) denom[m] = fmaxf(fmaxf(red[0], red[1]), fmaxf(red[2], red[3]));
}

// ---------------------------------------------------------------------------
// down split-K reduce: out = part0 + part1 + bias + x
// ---------------------------------------------------------------------------
__global__ __launch_bounds__(256) void down_reduce(
    const float* __restrict__ part, const float* __restrict__ x,
    const float* __restrict__ bias, float* __restrict__ out)
{
  const size_t idx = ((size_t)blockIdx.x * 256 + threadIdx.x) * 4;
  const size_t P = (size_t)B_ * IN_;
  f32x4 a = *(const f32x4*)(part + idx);
  f32x4 b = *(const f32x4*)(part + P + idx);
  f32x4 xv = *(const f32x4*)(x + idx);
  const int j = (int)(idx & (IN_ - 1));
  f32x4 bv = *(const f32x4*)(bias + j);
  f32x4 o;
#pragma unroll
  for (int e = 0; e < 4; ++e) o[e] = a[e] + b[e] + bv[e] + xv[e];
  *(f32x4*)(out + idx) = o;
}

// ---------------------------------------------------------------------------
// Batched weight convert+transpose: ALL 10 weights in ONE dispatch (r8).
// Compile-time descriptor table; tile id -> (weight, z, bx, by).
// ---------------------------------------------------------------------------
struct TP {
  const float* src[10];
  unsigned short* dst[10];
};

__global__ __launch_bounds__(256) void transpose_all(TP p)
{
  __shared__ float tile[32][33];
  const int tid = blockIdx.x;
  int w, base, R, C, izoff, ozoff;
  if      (tid < 2048)  { w = 0; base = 0;     R = 1024; C = 2048; izoff = 0;     ozoff = 0; }
  else if (tid < 4096)  { w = 1; base = 2048;  R = 1024; C = 2048; izoff = 0;     ozoff = 0; }
  else if (tid < 8192)  { w = 2; base = 4096;  R = 2048; C = 2048; izoff = 0;     ozoff = 0; }
  else if (tid < 12288) { w = 3; base = 8192;  R = 2048; C = 2048; izoff = 0;     ozoff = 0; }
  else if (tid < 16384) { w = 4; base = 12288; R = 2048; C = 2048; izoff = 0;     ozoff = 0; }
  else if (tid < 16896) { w = 5; base = 16384; R = 256;  C = 256;  izoff = 65536; ozoff = 131072; }
  else if (tid < 17408) { w = 6; base = 16896; R = 256;  C = 256;  izoff = 65536; ozoff = 131072; }
  else if (tid < 17920) { w = 7; base = 17408; R = 256;  C = 256;  izoff = 65536; ozoff = 65536; }
  else if (tid < 22016) { w = 8; base = 17920; R = 2048; C = 2048; izoff = 0;     ozoff = 0; }
  else                  { w = 9; base = 22016; R = 2048; C = 1024; izoff = 0;     ozoff = 0; }
  const int local = tid - base;
  const int cx = C >> 5;
  const int tpz = cx * (R >> 5);
  const int z = local / tpz;
  const int rem = local % tpz;
  const int bx = rem % cx, by = rem / cx;
  const float* in = p.src[w] + (size_t)z * izoff;
  unsigned short* out = p.dst[w] + (size_t)z * ozoff;
  const int cb = bx * 32, rb = by * 32;
  const int tx = threadIdx.x & 31, ty = threadIdx.x >> 5;
  for (int i = ty; i < 32; i += 8)
    tile[i][tx] = in[(size_t)(rb + i) * C + cb + tx];
  __syncthreads();
  for (int i = ty; i < 32; i += 8)
    out[(size_t)(cb + i) * R + rb + tx] = f2bf(tile[tx][i]);
}

// ---------------------------------------------------------------------------
// LayerNorm over 1024 features, one block per row, write bf16.
// ---------------------------------------------------------------------------
__global__ __launch_bounds__(256) void ln_kernel(
    const float* __restrict__ x, const float* __restrict__ g,
    const float* __restrict__ b, unsigned short* __restrict__ xn)
{
  const int brow = blockIdx.x, t = threadIdx.x;
  const int lane = t & 63, wave = t >> 6;
  const float* xr = x + (size_t)brow * IN_;
  f32x4 v = *(const f32x4*)(xr + t * 4);
  float s = v[0] + v[1] + v[2] + v[3];
  float q = v[0]*v[0] + v[1]*v[1] + v[2]*v[2] + v[3]*v[3];
#pragma unroll
  for (int off = 32; off; off >>= 1) {
    s += __shfl_xor(s, off, 64);
    q += __shfl_xor(q, off, 64);
  }
  __shared__ float ss[4], sq[4];
  if (lane == 0) { ss[wave] = s; sq[wave] = q; }
  __syncthreads();
  s = ss[0] + ss[1] + ss[2] + ss[3];
  q = sq[0] + sq[1] + sq[2] + sq[3];
  const float mean = s * (1.f / IN_);
  const float var = q * (1.f / IN_) - mean * mean;
  const float rs = rsqrtf(var + EPS_);
  u16x4 o;
#pragma unroll
  for (int e = 0; e < 4; ++e) {
    const int j = t * 4 + e;
    o[e] = f2bf((v[e] - mean) * rs * g[j] + b[j]);
  }
  *(u16x4*)(xn + (size_t)brow * IN_ + t * 4) = o;
}

// ---------------------------------------------------------------------------
// Causal conv1d (k=4, left pad 3) along features + SiLU. One block per row.
// ---------------------------------------------------------------------------
__global__ __launch_bounds__(256) void conv_kernel(
    const unsigned short* __restrict__ xul, const float* __restrict__ cw,
    const float* __restrict__ cb, unsigned short* __restrict__ xc)
{
  const int brow = blockIdx.x, t = threadIdx.x;
  const size_t base = (size_t)brow * UP_;
  const int j0 = t * 8;
  float xv[11];
#pragma unroll
  for (int e = 0; e < 11; ++e) {
    const int j = j0 + e - 3;
    xv[e] = (j >= 0) ? bf2f(xul[base + j]) : 0.f;
  }
  const float w0 = cw[0], w1 = cw[1], w2 = cw[2], w3 = cw[3], bb = cb[0];
  u16x8 o;
#pragma unroll
  for (int e = 0; e < 8; ++e) {
    float sv = bb + w0 * xv[e] + w1 * xv[e + 1] + w2 * xv[e + 2] + w3 * xv[e + 3];
    o[e] = f2bf(sv / (1.f + expf(-sv)));
  }
  *(u16x8*)(xc + base + j0) = o;
}

// ---------------------------------------------------------------------------
// Gates, 64x64 tile per block: m_t,c_t,n_t fp32 + nT AND qT bf16 (LDS
// transpose, r8: q-transpose fused here, standalone dispatch removed).
// i/f read as bf16 from merged sif buffer [B][6144] (i at +2048, f +4096).
// ---------------------------------------------------------------------------
__global__ __launch_bounds__(256) void gates_kernel(
    const unsigned short* __restrict__ sif,
    const unsigned short* __restrict__ kb, const unsigned short* __restrict__ vb,
    const unsigned short* __restrict__ qb,
    const float* __restrict__ mprev, const float* __restrict__ cprev,
    const float* __restrict__ nprev,
    float* __restrict__ mo, float* __restrict__ co, float* __restrict__ no,
    unsigned short* __restrict__ nT, unsigned short* __restrict__ qT)
{
  __shared__ unsigned short nt_t[64][72];
  __shared__ unsigned short qt_t[64][72];
  const int t = threadIdx.x;
  const int r = t >> 2, cq = t & 3;
  const int row = blockIdx.y * 64 + r;
  const int colb = blockIdx.x * 64 + cq * 16;
  const size_t hidb = (size_t)row * HID_ + colb;
  const size_t sifb = (size_t)row * 6144 + colb;
#pragma unroll
  for (int e4 = 0; e4 < 4; ++e4) {
    const int c4 = e4 * 4;
    f32x4 mp = *(const f32x4*)(mprev + hidb + c4);
    f32x4 cp = *(const f32x4*)(cprev + hidb + c4);
    f32x4 np = *(const f32x4*)(nprev + hidb + c4);
    u16x4 iv = *(const u16x4*)(sif + sifb + 2048 + c4);
    u16x4 fv = *(const u16x4*)(sif + sifb + 4096 + c4);
    u16x4 kv = *(const u16x4*)(kb + hidb + c4);
    u16x4 vv = *(const u16x4*)(vb + hidb + c4);
    u16x4 qv = *(const u16x4*)(qb + hidb + c4);
    f32x4 mo4, co4, no4;
#pragma unroll
    for (int e = 0; e < 4; ++e) {
      const float ft = bf2f(fv[e]) + mp[e];
      const float it = bf2f(iv[e]);
      const float mt = fmaxf(ft, it);
      const float ie = expf(it - mt);
      const float fe = expf(ft - mt);
      const float k = bf2f(kv[e]), v = bf2f(vv[e]);
      mo4[e] = mt;
      co4[e] = fe * cp[e] + ie * (v * k);
      no4[e] = fe * np[e] + ie * k;
      nt_t[r][cq * 16 + c4 + e] = f2bf(no4[e]);
      qt_t[r][cq * 16 + c4 + e] = qv[e];
    }
    *(f32x4*)(mo + hidb + c4) = mo4;
    *(f32x4*)(co + hidb + c4) = co4;
    *(f32x4*)(no + hidb + c4) = no4;
  }
  __syncthreads();
  // transposed writes: nT[col][row], qT[col][row]
  const int cT = t >> 2, sq = t & 3;
  u16x8 o0, o1, p0, p1;
#pragma unroll
  for (int e = 0; e < 8; ++e) {
    o0[e] = nt_t[sq * 16 + e][cT];
    o1[e] = nt_t[sq * 16 + 8 + e][cT];
    p0[e] = qt_t[sq * 16 + e][cT];
    p1[e] = qt_t[sq * 16 + 8 + e][cT];
  }
  const size_t ob = (size_t)(blockIdx.x * 64 + cT) * B_ + blockIdx.y * 64 + sq * 16;
  *(u16x8*)(nT + ob) = o0;
  *(u16x8*)(nT + ob + 8) = o1;
  *(u16x8*)(qT + ob) = p0;
  *(u16x8*)(qT + ob + 8) = p1;
}

// ---------------------------------------------------------------------------
// h_t = o*c_t*q/denom; GroupNorm (8 groups of 256); pre = (hn+skip)*silu(xur).
// skip read from merged sif buffer (row stride 6144, cols 0..2047).
// ---------------------------------------------------------------------------
__global__ __launch_bounds__(256) void hgn_kernel(
    const float* __restrict__ ct, const unsigned short* __restrict__ olin,
    const unsigned short* __restrict__ qb, const float* __restrict__ denom,
    const unsigned short* __restrict__ sif, const unsigned short* __restrict__ xurb,
    const float* __restrict__ gng, const float* __restrict__ gnb,
    float* __restrict__ ho, unsigned short* __restrict__ pre)
{
  const int brow = blockIdx.x, t = threadIdx.x;
  const size_t base = (size_t)brow * HID_ + t * 8;
  u16x8 ov = *(const u16x8*)(olin + base);
  u16x8 qv = *(const u16x8*)(qb + base);
  f32x4 c0 = *(const f32x4*)(ct + base);
  f32x4 c1 = *(const f32x4*)(ct + base + 4);
  float h[8];
  float s = 0.f, sq = 0.f;
#pragma unroll
  for (int e = 0; e < 8; ++e) {
    const float o = 1.f / (1.f + expf(-bf2f(ov[e])));
    const float cv = (e < 4) ? c0[e] : c1[e - 4];
    const float hv = o * cv * bf2f(qv[e]) / denom[t * 8 + e];
    h[e] = hv; s += hv; sq += hv * hv;
  }
#pragma unroll
  for (int e = 0; e < 8; ++e) ho[base + e] = h[e];
#pragma unroll
  for (int off = 1; off < 32; off <<= 1) {
    s += __shfl_xor(s, off, 64);
    sq += __shfl_xor(sq, off, 64);
  }
  const float mean = s * (1.f / HS_);
  const float var = sq * (1.f / HS_) - mean * mean;
  const float rs = rsqrtf(var + EPS_);
  u16x8 sv = *(const u16x8*)(sif + (size_t)brow * 6144 + t * 8);
  u16x8 xv = *(const u16x8*)(xurb + base);
  u16x8 pv;
#pragma unroll
  for (int e = 0; e < 8; ++e) {
    const int j = t * 8 + e;
    const float hn = (h[e] - mean) * rs * gng[j] + gnb[j];
    const float xr = bf2f(xv[e]);
    const float sil = xr / (1.f + expf(-xr));
    pv[e] = f2bf((hn + bf2f(sv[e])) * sil);
  }
  *(u16x8*)(pre + base) = pv;
}

// ---------------------------------------------------------------------------
extern "C" void kernel_launch(void* const* d_in, const int* in_sizes, int n_in,
                              void* d_out, int out_size, void* d_ws, size_t ws_size,
                              hipStream_t stream)
{
  const float* x      = (const float*)d_in[0];
  const float* c_prev = (const float*)d_in[2];
  const float* n_prev = (const float*)d_in[3];
  const float* m_prev = (const float*)d_in[4];
  const float* ln_g   = (const float*)d_in[5];
  const float* ln_b   = (const float*)d_in[6];
  const float* w_ul   = (const float*)d_in[7];
  const float* b_ul   = (const float*)d_in[8];
  const float* w_ur   = (const float*)d_in[9];
  const float* b_ur   = (const float*)d_in[10];
  const float* conv_w = (const float*)d_in[11];
  const float* conv_b = (const float*)d_in[12];
  const float* w_skip = (const float*)d_in[13];
  const float* b_skip = (const float*)d_in[14];
  const float* w_q    = (const float*)d_in[15];
  const float* b_q    = (const float*)d_in[16];
  const float* w_k    = (const float*)d_in[17];
  const float* b_k    = (const float*)d_in[18];
  const float* w_v    = (const float*)d_in[19];
  const float* b_v    = (const float*)d_in[20];
  const float* w_i    = (const float*)d_in[21];
  const float* b_i    = (const float*)d_in[22];
  const float* w_f    = (const float*)d_in[23];
  const float* b_f    = (const float*)d_in[24];
  const float* w_o    = (const float*)d_in[25];
  const float* b_o    = (const float*)d_in[26];
  const float* gn_g   = (const float*)d_in[27];
  const float* gn_b   = (const float*)d_in[28];
  const float* w_down = (const float*)d_in[29];
  const float* b_down = (const float*)d_in[30];

  float* out_p = (float*)d_out;                       // [B, IN]
  float* h_p = out_p + (size_t)B_ * IN_;              // [B, HID]
  float* c_p = h_p + (size_t)B_ * HID_;
  float* n_p = c_p + (size_t)B_ * HID_;
  float* m_p = n_p + (size_t)B_ * HID_;

  char* ws = (char*)d_ws;
  size_t off = 0;
  auto alloc = [&](size_t n) -> void* {
    void* p = ws + off;
    off += (n + 255) & ~(size_t)255;
    return p;
  };

  const size_t BH2 = (size_t)B_ * HID_ * 2;

  unsigned short* xn_bf   = (unsigned short*)alloc((size_t)B_ * IN_ * 2);
  unsigned short* xul_bf  = (unsigned short*)alloc(BH2);
  unsigned short* xur_bf  = (unsigned short*)alloc(BH2);
  unsigned short* xc_bf   = (unsigned short*)alloc(BH2);
  unsigned short* sif_bf  = (unsigned short*)alloc((size_t)B_ * 6144 * 2);
  unsigned short* q_bf    = (unsigned short*)alloc(BH2);
  unsigned short* k_bf    = (unsigned short*)alloc(BH2);
  unsigned short* v_bf    = (unsigned short*)alloc(BH2);
  unsigned short* olin_bf = (unsigned short*)alloc(BH2);
  unsigned short* qT_bf   = (unsigned short*)alloc(BH2);
  unsigned short* nT_bf   = (unsigned short*)alloc(BH2);
  unsigned short* pre_bf  = (unsigned short*)alloc(BH2);
  float* denom = (float*)alloc(HID_ * sizeof(float));
  float* part  = (float*)alloc((size_t)4 * HID_ * HID_ * sizeof(float));
  float* b_sif = (float*)alloc(6144 * sizeof(float));
  unsigned short* wt_ulur = (unsigned short*)alloc((size_t)4096 * IN_ * 2);
  unsigned short* wt_sif  = (unsigned short*)alloc((size_t)6144 * UP_ * 2);
  unsigned short* wt_qk   = (unsigned short*)alloc((size_t)H_ * 512 * HS_ * 2);
  unsigned short* wt_v    = (unsigned short*)alloc((size_t)H_ * HS_ * HS_ * 2);
  unsigned short* wt_o    = (unsigned short*)alloc((size_t)UP_ * HID_ * 2);
  unsigned short* wt_down = (unsigned short*)alloc((size_t)HID_ * IN_ * 2);

  if (off > ws_size) return;  // fail loudly (poisoned output) rather than OOB

  const int NOSPLIT = 1 << 30;

  // ---- stacked biases (d2d async copies, graph-capture safe) ----
  hipMemcpyAsync(b_sif, b_skip, 2048 * 4, hipMemcpyDeviceToDevice, stream);
  hipMemcpyAsync(b_sif + 2048, b_i, 2048 * 4, hipMemcpyDeviceToDevice, stream);
  hipMemcpyAsync(b_sif + 4096, b_f, 2048 * 4, hipMemcpyDeviceToDevice, stream);

  // ---- ALL weight transposes in one dispatch ----
  TP tp;
  tp.src[0] = w_ul;   tp.dst[0] = wt_ulur;
  tp.src[1] = w_ur;   tp.dst[1] = wt_ulur + (size_t)2048 * 1024;
  tp.src[2] = w_skip; tp.dst[2] = wt_sif;
  tp.src[3] = w_i;    tp.dst[3] = wt_sif + (size_t)2048 * 2048;
  tp.src[4] = w_f;    tp.dst[4] = wt_sif + (size_t)4096 * 2048;
  tp.src[5] = w_q;    tp.dst[5] = wt_qk;
  tp.src[6] = w_k;    tp.dst[6] = wt_qk + 65536;
  tp.src[7] = w_v;    tp.dst[7] = wt_v;
  tp.src[8] = w_o;    tp.dst[8] = wt_o;
  tp.src[9] = w_down; tp.dst[9] = wt_down;
  transpose_all<<<24064, 256, 0, stream>>>(tp);

  // ---- LayerNorm ----
  ln_kernel<<<B_, 256, 0, stream>>>(x, ln_g, ln_b, xn_bf);

  // ---- merged up projections: [xul | xur] = xn @ [w_ul | w_ur] ----
  gemm8p<unsigned short, false><<<dim3(16, 32, 1), 512, 0, stream>>>(
      xn_bf, IN_, 0, wt_ulur, IN_, 0, b_ul, b_ur, 0,
      xul_bf, xur_bf, HID_, 0, 2048, nullptr, 1.f, 1.f, IN_);

  // ---- conv4 + silu ----
  conv_kernel<<<B_, 256, 0, stream>>>(xul_bf, conv_w, conv_b, xc_bf);

  // ---- merged skip|i|f from xc ----
  gemm8p<unsigned short, false><<<dim3(24, 32, 1), 512, 0, stream>>>(
      xc_bf, UP_, 0, wt_sif, UP_, 0, b_sif, nullptr, 0,
      sif_bf, sif_bf, 6144, 0, NOSPLIT, nullptr, 1.f, 1.f, UP_);

  // ---- merged q|k (blockdiag, per-head z), k scaled by 1/16 ----
  gemm8p<unsigned short, false><<<dim3(2, 32, 8), 512, 0, stream>>>(
      xc_bf, UP_, HS_, wt_qk, HS_, 512 * HS_, b_q, b_k, HS_,
      q_bf, k_bf, HID_, HS_, 256, nullptr, 1.f, 0.0625f, HS_);

  // ---- v (blockdiag from xul) ----
  gemm8p<unsigned short, false><<<dim3(1, 32, 8), 512, 0, stream>>>(
      xul_bf, UP_, HS_, wt_v, HS_, HS_ * HS_, b_v, nullptr, HS_,
      v_bf, v_bf, HID_, HS_, NOSPLIT, nullptr, 1.f, 1.f, HS_);

  // ---- o-gate linear from xul ----
  gemm8p<unsigned short, false><<<dim3(8, 32, 1), 512, 0, stream>>>(
      xul_bf, UP_, 0, wt_o, UP_, 0, b_o, nullptr, 0,
      olin_bf, olin_bf, HID_, 0, NOSPLIT, nullptr, 1.f, 1.f, UP_);

  // ---- gates -> m_t, c_t, n_t (fp32 to d_out) + nT, qT bf16 ----
  gates_kernel<<<dim3(HID_ / 64, B_ / 64, 1), 256, 0, stream>>>(
      sif_bf, k_bf, v_bf, q_bf, m_prev, c_prev, n_prev,
      m_p, c_p, n_p, nT_bf, qT_bf);

  // ---- denom: split-K x4 partial GEMMs, then reduce ----
  gemm8p<float, false><<<dim3(8, 8, 4), 512, 0, stream>>>(
      nT_bf, B_, B_ / 4, qT_bf, B_, B_ / 4, nullptr, nullptr, 0,
      part, part, HID_, HID_ * HID_, NOSPLIT, nullptr, 1.f, 1.f, B_ / 4);
  denom_reduce<<<HID_, 256, 0, stream>>>(part, denom);

  // ---- h_t, GroupNorm, fuse with skip & silu(xur) ----
  hgn_kernel<<<B_, 256, 0, stream>>>(
      c_p, olin_bf, q_bf, denom, sif_bf, xur_bf, gn_g, gn_b, h_p, pre_bf);

  // ---- down projection: split-K x2 partials, then reduce(+bias+residual) ----
  gemm8p<float, false><<<dim3(4, 32, 2), 512, 0, stream>>>(
      pre_bf, UP_, 1024, wt_down, UP_, 1024, nullptr, nullptr, 0,
      part, part, IN_, B_ * IN_, NOSPLIT, nullptr, 1.f, 1.f, 1024);
  down_reduce<<<(B_ * IN_ / 4) / 256, 256, 0, stream>>>(part, x, b_down, out_p);
}

// Round 11
// 969.741 us; speedup vs baseline: 1.0584x; 1.0059x over previous
//
#include <hip/hip_runtime.h>
#include <stdint.h>

#define B_    8192
#define IN_   1024
#define HID_  2048
#define UP_   2048
#define H_    8
#define HS_   256
#define EPS_  1e-5f

typedef __bf16 bf16x8 __attribute__((ext_vector_type(8)));
typedef float f32x4 __attribute__((ext_vector_type(4)));
typedef unsigned short u16x4 __attribute__((ext_vector_type(4)));
typedef unsigned short u16x8 __attribute__((ext_vector_type(8)));

__device__ __forceinline__ unsigned short f2bf(float f) {
  union { float f; unsigned int u; } v; v.f = f;
  unsigned int u = v.u;
  unsigned int r = (u + 0x7fffu + ((u >> 16) & 1u)) >> 16;  // RNE
  return (unsigned short)r;
}
__device__ __forceinline__ float bf2f(unsigned short h) {
  union { unsigned int u; float f; } v; v.u = ((unsigned int)h) << 16;
  return v.f;
}

// global->LDS direct load, 16B per lane (guide §5; m97/m201 pattern).
__device__ __forceinline__ void gload_lds16(const void* g, void* l) {
  auto gp = reinterpret_cast<const uint32_t __attribute__((address_space(1)))*>(
      reinterpret_cast<uintptr_t>(g));
  auto lp = reinterpret_cast<uint32_t __attribute__((address_space(3)))*>(
      reinterpret_cast<uintptr_t>(l));
  __builtin_amdgcn_global_load_lds(gp, lp, 16, 0, 0);
}

#define SB0 __builtin_amdgcn_sched_barrier(0)

// A-fragment load (4 ds_read_b128) into a named register set (rule #20).
#define PREFETCH_AF(DST, BASE, MI0)                                         \
  DST[0][0] = *(const bf16x8*)((BASE) + (aRdBase + (MI0) * 2048));          \
  DST[0][1] = *(const bf16x8*)((BASE) + ((aRdBase + (MI0) * 2048) ^ 64));   \
  DST[1][0] = *(const bf16x8*)((BASE) + (aRdBase + ((MI0) + 1) * 2048));    \
  DST[1][1] = *(const bf16x8*)((BASE) + ((aRdBase + ((MI0) + 1) * 2048) ^ 64));

#define LOAD_BFR(BASE)                                                      \
  _Pragma("unroll")                                                         \
  for (int ni = 0; ni < 4; ++ni) {                                          \
    bfr[ni][0] = *(const bf16x8*)((BASE) + (bRdBase + ni * 2048));          \
    bfr[ni][1] = *(const bf16x8*)((BASE) + ((bRdBase + ni * 2048) ^ 64));   \
  }

#define MFMA_CLUSTER(AF, Q)                                                 \
  __builtin_amdgcn_s_setprio(1);                                           \
  _Pragma("unroll")                                                         \
  for (int kq = 0; kq < 2; ++kq)                                            \
    _Pragma("unroll")                                                       \
    for (int m2 = 0; m2 < 2; ++m2)                                          \
      _Pragma("unroll")                                                     \
      for (int ni = 0; ni < 4; ++ni)                                        \
        acc[(Q) * 2 + m2][ni] = __builtin_amdgcn_mfma_f32_16x16x32_bf16(    \
            AF[m2][kq], bfr[ni][kq], acc[(Q) * 2 + m2][ni], 0, 0, 0);       \
  __builtin_amdgcn_s_setprio(0);

// ---------------------------------------------------------------------------
// 256x256 bf16 GEMM, coarse-barrier tile schedule, RACE-FIXED (round 11).
// r7/r8 pre-issued next-tile frag ds_reads BEFORE the end-of-tile barrier —
// but vmcnt is WAVE-LOCAL, and the tile's LDS is DMA'd by all 8 waves, so a
// wave could read rows whose gload_lds (issued by ANOTHER wave) hadn't
// landed. Fix: ALL cross-wave LDS reads now sit strictly after a barrier
// that follows EVERY wave's retiring vmcnt (reads at loop-body top).
// C[m][col] = (sum_k A[m][k] * W[col][k] + bias[col]) * scale  [+ ADD]
// Split epilogue: col0 < c_split -> C/bias/scale, else C2/bias2/scale2.
// BM=BN=256, BK=64, 8 waves (2M x 4N), per-wave 128x64, acc[8][4] f32x4.
// LDS 160 KiB: A tri-buffer (T%3)*32K; B dual-buffer at +96K + (T&1)*32K.
// Per-wave lgkm ledger (in-order retirement):
//   body top: LOAD_BFR(8) + afA(4) + afB(4) = 16 outstanding
//   q0: lgkm(4) [B+afA done] ; MFMA(afA,0) ; read afA<-q2 ; gload A(T+2)h0
//   q1: lgkm(4) [afB done]   ; MFMA(afB,1) ; MID-BARRIER
//   read afB<-q3 ; gload A(T+2)h1 + B(T+2)h0,h1
//   q2: lgkm(4) [q2 done]    ; MFMA(afA,2)
//   q3: lgkm(0) [q3 done]    ; MFMA(afB,3)
//   vmcnt(8|0) [own T+1 DMA retired] ; BARRIER [=> ALL waves' T+1 retired]
// VM ledger at end-of-tile wait: T+1's 8 + T+2's 8 = 16 -> vmcnt(8).
// Write-hazard audit: A(T+2)->(T+2)%3 last read in tile T-1 (reads retired
// pre-T-1-end-barrier); B(T+2)->(T&1): B(T) reads retired by q0's lgkm(4)
// in every wave, hence before mid-barrier; gloads issue post-mid-barrier.
// ---------------------------------------------------------------------------
template <typename OutT, bool HAS_ADD>
__global__ __launch_bounds__(512, 2) void gemm8p(
    const unsigned short* __restrict__ A, int lda, int a_zoff,
    const unsigned short* __restrict__ W, int ldw, int w_zoff,
    const float* __restrict__ bias, const float* __restrict__ bias2,
    int bias_zoff,
    OutT* __restrict__ C, OutT* __restrict__ C2, int ldc, int c_zoff,
    int c_split,
    const float* __restrict__ ADD, float scale, float scale2, int K)
{
  __shared__ char lds[163840];
  const int z = blockIdx.z;
  A += (size_t)z * a_zoff;
  W += (size_t)z * w_zoff;
  if (bias) bias += (size_t)z * bias_zoff;
  if (bias2) bias2 += (size_t)z * bias_zoff;

  // T1: bijective XCD swizzle (m204 formula) on the flat per-z tile id.
  const int gx = gridDim.x, gy = gridDim.y;
  const int nwg = gx * gy;
  const int orig = blockIdx.y * gx + blockIdx.x;
  const int q8 = nwg >> 3, r8 = nwg & 7;
  const int xcd = orig & 7, xi = orig >> 3;
  const int wg = (xcd < r8 ? xcd * (q8 + 1) : r8 * (q8 + 1) + (xcd - r8) * q8) + xi;
  // r8: 8-tall row-group raster (bijective when 8 | gy, guard otherwise)
  int bx, by;
  if ((gy & 7) == 0) {
    const int per = gx * 8;
    const int g0 = (wg / per) * 8;
    const int rem = wg % per;
    bx = rem >> 3;
    by = g0 + (rem & 7);
  } else {
    bx = wg % gx;
    by = wg / gx;
  }

  const int t = threadIdx.x;
  const int lane = t & 63, wave = t >> 6;     // 8 waves
  const int wr = wave >> 2, wc = wave & 3;    // 2 x 4
  const int l15 = lane & 15, l4 = lane >> 4;
  const int row0 = by * 256, col0 = bx * 256;

  // staging per-lane invariants (pre-swizzled source slot)
  const int lrow = lane >> 3;                  // 0..7
  const int lslot = (lane & 7) ^ lrow;         // involution per row parity
  const size_t aLane = (size_t)lrow * lda * 2 + (size_t)lslot * 16;
  const size_t wLane = (size_t)lrow * ldw * 2 + (size_t)lslot * 16;
  const char* Abase = (const char*)A;
  const char* Wbase = (const char*)W;

  // ds_read per-lane base byte offsets within a tile (kq=0); kq=1 is ^64
  const int aRdBase = (wr * 128 + l15) * 128 + (((l4) ^ (l15 & 7)) * 16);
  const int bRdBase = (wc * 64 + l15) * 128 + (((l4) ^ (l15 & 7)) * 16);

  auto issueA = [&](int abuf, int half, int tile) {
#pragma unroll
    for (int j = 0; j < 2; ++j) {
      const int rbase = half * 128 + j * 64 + wave * 8;
      gload_lds16(Abase + (size_t)(row0 + rbase) * (lda * 2) + (size_t)tile * 128 + aLane,
                  lds + abuf * 32768 + rbase * 128 + lane * 16);
    }
  };
  auto issueB = [&](int bbuf, int half, int tile) {
#pragma unroll
    for (int j = 0; j < 2; ++j) {
      const int rbase = half * 128 + j * 64 + wave * 8;
      gload_lds16(Wbase + (size_t)(col0 + rbase) * (ldw * 2) + (size_t)tile * 128 + wLane,
                  lds + 98304 + bbuf * 32768 + rbase * 128 + lane * 16);
    }
  };

  f32x4 acc[8][4] = {};
  const int NT = K >> 6;

  bf16x8 bfr[4][2];             // B-frags for current tile (8 b128)
  bf16x8 afA[2][2], afB[2][2];  // A-frag ping-pong (4+4 b128)

  // ---- prologue: stage tile0+tile1; retire OWN tile0 DMA; barrier makes
  // ALL waves' tile0 DMA visible. NO LDS reads before this barrier. ----
  issueA(0, 0, 0); issueA(0, 1, 0);
  issueB(0, 0, 0); issueB(0, 1, 0);
  if (NT > 1) {
    issueA(1, 0, 1); issueA(1, 1, 1);
    issueB(1, 0, 1); issueB(1, 1, 1);
    asm volatile("s_waitcnt vmcnt(8)" ::: "memory");   // own tile0 loads done
  } else {
    asm volatile("s_waitcnt vmcnt(0)" ::: "memory");
  }
  __builtin_amdgcn_s_barrier();                        // tile0 globally ready
  SB0;

  for (int T = 0; T < NT; ++T) {
    const char* ldsA = lds + (T % 3) * 32768;
    const char* ldsB = lds + 98304 + (T & 1) * 32768;
    const int abufN = (T + 2) % 3;
    const int bbufN = T & 1;                   // == (T+2)&1
    // ---- body top: issue this tile's B-frags + q0/q1 A-frags (16 ds) ----
    LOAD_BFR(ldsB)
    PREFETCH_AF(afA, ldsA, 0)
    PREFETCH_AF(afB, ldsA, 2)
    SB0;
    // q0: B + afA done (16 -> 4: afB pending)
    asm volatile("s_waitcnt lgkmcnt(4)" ::: "memory"); SB0;
    MFMA_CLUSTER(afA, 0)
    PREFETCH_AF(afA, ldsA, 4)                  // q2 frags (drain under q1)
    if (T + 2 < NT) issueA(abufN, 0, T + 2);
    // q1: afB done (8 -> 4: q2 pending)
    asm volatile("s_waitcnt lgkmcnt(4)" ::: "memory"); SB0;
    MFMA_CLUSTER(afB, 1)
    __builtin_amdgcn_s_barrier();              // mid-tile: B(T) reads complete
    SB0;
    PREFETCH_AF(afB, ldsA, 6)                  // q3 frags (drain under q2)
    if (T + 2 < NT) {
      issueA(abufN, 1, T + 2);
      issueB(bbufN, 0, T + 2);                 // safe: post-mid-barrier
      issueB(bbufN, 1, T + 2);
    }
    // q2: q2 frags done (8 -> 4: q3 pending)
    asm volatile("s_waitcnt lgkmcnt(4)" ::: "memory"); SB0;
    MFMA_CLUSTER(afA, 2)
    asm volatile("s_waitcnt lgkmcnt(0)" ::: "memory"); SB0;
    MFMA_CLUSTER(afB, 3)
    // tile boundary: retire OWN T+1 DMA (keep T+2 in flight), then barrier
    // => next iteration's reads see ALL waves' T+1 data. NO reads here.
    if (T + 2 < NT) asm volatile("s_waitcnt vmcnt(8)" ::: "memory");
    else            asm volatile("s_waitcnt vmcnt(0)" ::: "memory");
    SB0;
    __builtin_amdgcn_s_barrier();
    SB0;
  }

  // epilogue: C/D layout col=lane&15, row=(lane>>4)*4+reg (guide §3)
  const float* bp = bias;
  OutT* Cp = C;
  int cbase = col0;
  float sc = scale;
  if (col0 >= c_split) { bp = bias2; Cp = C2; cbase = col0 - c_split; sc = scale2; }
#pragma unroll
  for (int mi = 0; mi < 8; ++mi) {
#pragma unroll
    for (int ni = 0; ni < 4; ++ni) {
#pragma unroll
      for (int r = 0; r < 4; ++r) {
        const int m = row0 + wr * 128 + mi * 16 + l4 * 4 + r;
        const int n = wc * 64 + ni * 16 + l15;
        float v = acc[mi][ni][r];
        if (bp) v += bp[cbase + n];
        v *= sc;
        const size_t ci = (size_t)m * ldc + (size_t)z * c_zoff + cbase + n;
        if constexpr (HAS_ADD) v += ADD[ci];
        if constexpr (sizeof(OutT) == 2) Cp[ci] = (OutT)f2bf(v);
        else Cp[ci] = v;
      }
    }
  }
}

// ---------------------------------------------------------------------------
// denom[m] = max_n | sum_z part[z][m][n] |   (split-K reduction), one block/row
// ---------------------------------------------------------------------------
__global__ __launch_bounds__(256) void denom_reduce(
    const float* __restrict__ part, float* __restrict__ denom)
{
  const int m = blockIdx.x, t = threadIdx.x;
  const size_t P = (size_t)HID_ * HID_;
  float v = 0.f;
  for (int n = t; n < HID_; n += 256) {
    const size_t o = (size_t)m * HID_ + n;
    float s = part[o] + part[P + o] + part[2 * P + o] + part[3 * P + o];
    v = fmaxf(v, fabsf(s));
  }
#pragma unroll
  for (int off = 1; off < 64; off <<= 1) v = fmaxf(v, __shfl_xor(v, off, 64));
  __shared__ float red[4];
  if ((t & 63) == 0) red[t >> 6] = v;
  __syncthreads();
  if (t == 0) denom[m] = fmaxf(fmaxf(red[0], red[1]), fmaxf(red[2], red[3]));
}

// ---------------------------------------------------------------------------
// down split-K reduce: out = part0 + part1 + bias + x
// ---------------------------------------------------------------------------
__global__ __launch_bounds__(256) void down_reduce(
    const float* __restrict__ part, const float* __restrict__ x,
    const float* __restrict__ bias, float* __restrict__ out)
{
  const size_t idx = ((size_t)blockIdx.x * 256 + threadIdx.x) * 4;
  const size_t P = (size_t)B_ * IN_;
  f32x4 a = *(const f32x4*)(part + idx);
  f32x4 b = *(const f32x4*)(part + P + idx);
  f32x4 xv = *(const f32x4*)(x + idx);
  const int j = (int)(idx & (IN_ - 1));
  f32x4 bv = *(const f32x4*)(bias + j);
  f32x4 o;
#pragma unroll
  for (int e = 0; e < 4; ++e) o[e] = a[e] + b[e] + bv[e] + xv[e];
  *(f32x4*)(out + idx) = o;
}

// ---------------------------------------------------------------------------
// Batched weight convert+transpose: ALL 10 weights in ONE dispatch (r8).
// ---------------------------------------------------------------------------
struct TP {
  const float* src[10];
  unsigned short* dst[10];
};

__global__ __launch_bounds__(256) void transpose_all(TP p)
{
  __shared__ float tile[32][33];
  const int tid = blockIdx.x;
  int w, base, R, C, izoff, ozoff;
  if      (tid < 2048)  { w = 0; base = 0;     R = 1024; C = 2048; izoff = 0;     ozoff = 0; }
  else if (tid < 4096)  { w = 1; base = 2048;  R = 1024; C = 2048; izoff = 0;     ozoff = 0; }
  else if (tid < 8192)  { w = 2; base = 4096;  R = 2048; C = 2048; izoff = 0;     ozoff = 0; }
  else if (tid < 12288) { w = 3; base = 8192;  R = 2048; C = 2048; izoff = 0;     ozoff = 0; }
  else if (tid < 16384) { w = 4; base = 12288; R = 2048; C = 2048; izoff = 0;     ozoff = 0; }
  else if (tid < 16896) { w = 5; base = 16384; R = 256;  C = 256;  izoff = 65536; ozoff = 131072; }
  else if (tid < 17408) { w = 6; base = 16896; R = 256;  C = 256;  izoff = 65536; ozoff = 131072; }
  else if (tid < 17920) { w = 7; base = 17408; R = 256;  C = 256;  izoff = 65536; ozoff = 65536; }
  else if (tid < 22016) { w = 8; base = 17920; R = 2048; C = 2048; izoff = 0;     ozoff = 0; }
  else                  { w = 9; base = 22016; R = 2048; C = 1024; izoff = 0;     ozoff = 0; }
  const int local = tid - base;
  const int cx = C >> 5;
  const int tpz = cx * (R >> 5);
  const int z = local / tpz;
  const int rem = local % tpz;
  const int bx = rem % cx, by = rem / cx;
  const float* in = p.src[w] + (size_t)z * izoff;
  unsigned short* out = p.dst[w] + (size_t)z * ozoff;
  const int cb = bx * 32, rb = by * 32;
  const int tx = threadIdx.x & 31, ty = threadIdx.x >> 5;
  for (int i = ty; i < 32; i += 8)
    tile[i][tx] = in[(size_t)(rb + i) * C + cb + tx];
  __syncthreads();
  for (int i = ty; i < 32; i += 8)
    out[(size_t)(cb + i) * R + rb + tx] = f2bf(tile[tx][i]);
}

// ---------------------------------------------------------------------------
// LayerNorm over 1024 features, one block per row, write bf16.
// ---------------------------------------------------------------------------
__global__ __launch_bounds__(256) void ln_kernel(
    const float* __restrict__ x, const float* __restrict__ g,
    const float* __restrict__ b, unsigned short* __restrict__ xn)
{
  const int brow = blockIdx.x, t = threadIdx.x;
  const int lane = t & 63, wave = t >> 6;
  const float* xr = x + (size_t)brow * IN_;
  f32x4 v = *(const f32x4*)(xr + t * 4);
  float s = v[0] + v[1] + v[2] + v[3];
  float q = v[0]*v[0] + v[1]*v[1] + v[2]*v[2] + v[3]*v[3];
#pragma unroll
  for (int off = 32; off; off >>= 1) {
    s += __shfl_xor(s, off, 64);
    q += __shfl_xor(q, off, 64);
  }
  __shared__ float ss[4], sq[4];
  if (lane == 0) { ss[wave] = s; sq[wave] = q; }
  __syncthreads();
  s = ss[0] + ss[1] + ss[2] + ss[3];
  q = sq[0] + sq[1] + sq[2] + sq[3];
  const float mean = s * (1.f / IN_);
  const float var = q * (1.f / IN_) - mean * mean;
  const float rs = rsqrtf(var + EPS_);
  u16x4 o;
#pragma unroll
  for (int e = 0; e < 4; ++e) {
    const int j = t * 4 + e;
    o[e] = f2bf((v[e] - mean) * rs * g[j] + b[j]);
  }
  *(u16x4*)(xn + (size_t)brow * IN_ + t * 4) = o;
}

// ---------------------------------------------------------------------------
// Causal conv1d (k=4, left pad 3) + SiLU. One block per row.
// Vectorized: one u16x8 + one u16x4 (left-neighbor, zero for t==0). (G13)
// ---------------------------------------------------------------------------
__global__ __launch_bounds__(256) void conv_kernel(
    const unsigned short* __restrict__ xul, const float* __restrict__ cw,
    const float* __restrict__ cb, unsigned short* __restrict__ xc)
{
  const int brow = blockIdx.x, t = threadIdx.x;
  const size_t base = (size_t)brow * UP_;
  const int j0 = t * 8;
  u16x8 main8 = *(const u16x8*)(xul + base + j0);
  u16x4 prev4 = {0, 0, 0, 0};
  if (t > 0) prev4 = *(const u16x4*)(xul + base + j0 - 4);
  float xv[11];
  xv[0] = bf2f(prev4[1]);
  xv[1] = bf2f(prev4[2]);
  xv[2] = bf2f(prev4[3]);
#pragma unroll
  for (int e = 0; e < 8; ++e) xv[3 + e] = bf2f(main8[e]);
  const float w0 = cw[0], w1 = cw[1], w2 = cw[2], w3 = cw[3], bb = cb[0];
  u16x8 o;
#pragma unroll
  for (int e = 0; e < 8; ++e) {
    float sv = bb + w0 * xv[e] + w1 * xv[e + 1] + w2 * xv[e + 2] + w3 * xv[e + 3];
    o[e] = f2bf(sv / (1.f + expf(-sv)));
  }
  *(u16x8*)(xc + base + j0) = o;
}

// ---------------------------------------------------------------------------
// Gates, 64x64 tile per block: m_t,c_t,n_t fp32 + nT AND qT bf16 (LDS
// transpose; q-transpose fused, r8).
// ---------------------------------------------------------------------------
__global__ __launch_bounds__(256) void gates_kernel(
    const unsigned short* __restrict__ sif,
    const unsigned short* __restrict__ kb, const unsigned short* __restrict__ vb,
    const unsigned short* __restrict__ qb,
    const float* __restrict__ mprev, const float* __restrict__ cprev,
    const float* __restrict__ nprev,
    float* __restrict__ mo, float* __restrict__ co, float* __restrict__ no,
    unsigned short* __restrict__ nT, unsigned short* __restrict__ qT)
{
  __shared__ unsigned short nt_t[64][72];
  __shared__ unsigned short qt_t[64][72];
  const int t = threadIdx.x;
  const int r = t >> 2, cq = t & 3;
  const int row = blockIdx.y * 64 + r;
  const int colb = blockIdx.x * 64 + cq * 16;
  const size_t hidb = (size_t)row * HID_ + colb;
  const size_t sifb = (size_t)row * 6144 + colb;
#pragma unroll
  for (int e4 = 0; e4 < 4; ++e4) {
    const int c4 = e4 * 4;
    f32x4 mp = *(const f32x4*)(mprev + hidb + c4);
    f32x4 cp = *(const f32x4*)(cprev + hidb + c4);
    f32x4 np = *(const f32x4*)(nprev + hidb + c4);
    u16x4 iv = *(const u16x4*)(sif + sifb + 2048 + c4);
    u16x4 fv = *(const u16x4*)(sif + sifb + 4096 + c4);
    u16x4 kv = *(const u16x4*)(kb + hidb + c4);
    u16x4 vv = *(const u16x4*)(vb + hidb + c4);
    u16x4 qv = *(const u16x4*)(qb + hidb + c4);
    f32x4 mo4, co4, no4;
#pragma unroll
    for (int e = 0; e < 4; ++e) {
      const float ft = bf2f(fv[e]) + mp[e];
      const float it = bf2f(iv[e]);
      const float mt = fmaxf(ft, it);
      const float ie = expf(it - mt);
      const float fe = expf(ft - mt);
      const float k = bf2f(kv[e]), v = bf2f(vv[e]);
      mo4[e] = mt;
      co4[e] = fe * cp[e] + ie * (v * k);
      no4[e] = fe * np[e] + ie * k;
      nt_t[r][cq * 16 + c4 + e] = f2bf(no4[e]);
      qt_t[r][cq * 16 + c4 + e] = qv[e];
    }
    *(f32x4*)(mo + hidb + c4) = mo4;
    *(f32x4*)(co + hidb + c4) = co4;
    *(f32x4*)(no + hidb + c4) = no4;
  }
  __syncthreads();
  const int cT = t >> 2, sq = t & 3;
  u16x8 o0, o1, p0, p1;
#pragma unroll
  for (int e = 0; e < 8; ++e) {
    o0[e] = nt_t[sq * 16 + e][cT];
    o1[e] = nt_t[sq * 16 + 8 + e][cT];
    p0[e] = qt_t[sq * 16 + e][cT];
    p1[e] = qt_t[sq * 16 + 8 + e][cT];
  }
  const size_t ob = (size_t)(blockIdx.x * 64 + cT) * B_ + blockIdx.y * 64 + sq * 16;
  *(u16x8*)(nT + ob) = o0;
  *(u16x8*)(nT + ob + 8) = o1;
  *(u16x8*)(qT + ob) = p0;
  *(u16x8*)(qT + ob + 8) = p1;
}

// ---------------------------------------------------------------------------
// h_t = o*c_t*q/denom; GroupNorm (8 groups of 256); pre = (hn+skip)*silu(xur).
// ---------------------------------------------------------------------------
__global__ __launch_bounds__(256) void hgn_kernel(
    const float* __restrict__ ct, const unsigned short* __restrict__ olin,
    const unsigned short* __restrict__ qb, const float* __restrict__ denom,
    const unsigned short* __restrict__ sif, const unsigned short* __restrict__ xurb,
    const float* __restrict__ gng, const float* __restrict__ gnb,
    float* __restrict__ ho, unsigned short* __restrict__ pre)
{
  const int brow = blockIdx.x, t = threadIdx.x;
  const size_t base = (size_t)brow * HID_ + t * 8;
  u16x8 ov = *(const u16x8*)(olin + base);
  u16x8 qv = *(const u16x8*)(qb + base);
  f32x4 c0 = *(const f32x4*)(ct + base);
  f32x4 c1 = *(const f32x4*)(ct + base + 4);
  float h[8];
  float s = 0.f, sq = 0.f;
#pragma unroll
  for (int e = 0; e < 8; ++e) {
    const float o = 1.f / (1.f + expf(-bf2f(ov[e])));
    const float cv = (e < 4) ? c0[e] : c1[e - 4];
    const float hv = o * cv * bf2f(qv[e]) / denom[t * 8 + e];
    h[e] = hv; s += hv; sq += hv * hv;
  }
#pragma unroll
  for (int e = 0; e < 8; ++e) ho[base + e] = h[e];
#pragma unroll
  for (int off = 1; off < 32; off <<= 1) {
    s += __shfl_xor(s, off, 64);
    sq += __shfl_xor(sq, off, 64);
  }
  const float mean = s * (1.f / HS_);
  const float var = sq * (1.f / HS_) - mean * mean;
  const float rs = rsqrtf(var + EPS_);
  u16x8 sv = *(const u16x8*)(sif + (size_t)brow * 6144 + t * 8);
  u16x8 xv = *(const u16x8*)(xurb + base);
  u16x8 pv;
#pragma unroll
  for (int e = 0; e < 8; ++e) {
    const int j = t * 8 + e;
    const float hn = (h[e] - mean) * rs * gng[j] + gnb[j];
    const float xr = bf2f(xv[e]);
    const float sil = xr / (1.f + expf(-xr));
    pv[e] = f2bf((hn + bf2f(sv[e])) * sil);
  }
  *(u16x8*)(pre + base) = pv;
}

// ---------------------------------------------------------------------------
extern "C" void kernel_launch(void* const* d_in, const int* in_sizes, int n_in,
                              void* d_out, int out_size, void* d_ws, size_t ws_size,
                              hipStream_t stream)
{
  const float* x      = (const float*)d_in[0];
  const float* c_prev = (const float*)d_in[2];
  const float* n_prev = (const float*)d_in[3];
  const float* m_prev = (const float*)d_in[4];
  const float* ln_g   = (const float*)d_in[5];
  const float* ln_b   = (const float*)d_in[6];
  const float* w_ul   = (const float*)d_in[7];
  const float* b_ul   = (const float*)d_in[8];
  const float* w_ur   = (const float*)d_in[9];
  const float* b_ur   = (const float*)d_in[10];
  const float* conv_w = (const float*)d_in[11];
  const float* conv_b = (const float*)d_in[12];
  const float* w_skip = (const float*)d_in[13];
  const float* b_skip = (const float*)d_in[14];
  const float* w_q    = (const float*)d_in[15];
  const float* b_q    = (const float*)d_in[16];
  const float* w_k    = (const float*)d_in[17];
  const float* b_k    = (const float*)d_in[18];
  const float* w_v    = (const float*)d_in[19];
  const float* b_v    = (const float*)d_in[20];
  const float* w_i    = (const float*)d_in[21];
  const float* b_i    = (const float*)d_in[22];
  const float* w_f    = (const float*)d_in[23];
  const float* b_f    = (const float*)d_in[24];
  const float* w_o    = (const float*)d_in[25];
  const float* b_o    = (const float*)d_in[26];
  const float* gn_g   = (const float*)d_in[27];
  const float* gn_b   = (const float*)d_in[28];
  const float* w_down = (const float*)d_in[29];
  const float* b_down = (const float*)d_in[30];

  float* out_p = (float*)d_out;                       // [B, IN]
  float* h_p = out_p + (size_t)B_ * IN_;              // [B, HID]
  float* c_p = h_p + (size_t)B_ * HID_;
  float* n_p = c_p + (size_t)B_ * HID_;
  float* m_p = n_p + (size_t)B_ * HID_;

  char* ws = (char*)d_ws;
  size_t off = 0;
  auto alloc = [&](size_t n) -> void* {
    void* p = ws + off;
    off += (n + 255) & ~(size_t)255;
    return p;
  };

  const size_t BH2 = (size_t)B_ * HID_ * 2;

  unsigned short* xn_bf   = (unsigned short*)alloc((size_t)B_ * IN_ * 2);
  unsigned short* xul_bf  = (unsigned short*)alloc(BH2);
  unsigned short* xur_bf  = (unsigned short*)alloc(BH2);
  unsigned short* xc_bf   = (unsigned short*)alloc(BH2);
  unsigned short* sif_bf  = (unsigned short*)alloc((size_t)B_ * 6144 * 2);
  unsigned short* q_bf    = (unsigned short*)alloc(BH2);
  unsigned short* k_bf    = (unsigned short*)alloc(BH2);
  unsigned short* v_bf    = (unsigned short*)alloc(BH2);
  unsigned short* olin_bf = (unsigned short*)alloc(BH2);
  unsigned short* qT_bf   = (unsigned short*)alloc(BH2);
  unsigned short* nT_bf   = (unsigned short*)alloc(BH2);
  unsigned short* pre_bf  = (unsigned short*)alloc(BH2);
  float* denom = (float*)alloc(HID_ * sizeof(float));
  float* part  = (float*)alloc((size_t)4 * HID_ * HID_ * sizeof(float));
  float* b_sif = (float*)alloc(6144 * sizeof(float));
  unsigned short* wt_ulur = (unsigned short*)alloc((size_t)4096 * IN_ * 2);
  unsigned short* wt_sif  = (unsigned short*)alloc((size_t)6144 * UP_ * 2);
  unsigned short* wt_qk   = (unsigned short*)alloc((size_t)H_ * 512 * HS_ * 2);
  unsigned short* wt_v    = (unsigned short*)alloc((size_t)H_ * HS_ * HS_ * 2);
  unsigned short* wt_o    = (unsigned short*)alloc((size_t)UP_ * HID_ * 2);
  unsigned short* wt_down = (unsigned short*)alloc((size_t)HID_ * IN_ * 2);

  if (off > ws_size) return;  // fail loudly (poisoned output) rather than OOB

  const int NOSPLIT = 1 << 30;

  // ---- stacked biases (d2d async copies, graph-capture safe) ----
  hipMemcpyAsync(b_sif, b_skip, 2048 * 4, hipMemcpyDeviceToDevice, stream);
  hipMemcpyAsync(b_sif + 2048, b_i, 2048 * 4, hipMemcpyDeviceToDevice, stream);
  hipMemcpyAsync(b_sif + 4096, b_f, 2048 * 4, hipMemcpyDeviceToDevice, stream);

  // ---- ALL weight transposes in one dispatch ----
  TP tp;
  tp.src[0] = w_ul;   tp.dst[0] = wt_ulur;
  tp.src[1] = w_ur;   tp.dst[1] = wt_ulur + (size_t)2048 * 1024;
  tp.src[2] = w_skip; tp.dst[2] = wt_sif;
  tp.src[3] = w_i;    tp.dst[3] = wt_sif + (size_t)2048 * 2048;
  tp.src[4] = w_f;    tp.dst[4] = wt_sif + (size_t)4096 * 2048;
  tp.src[5] = w_q;    tp.dst[5] = wt_qk;
  tp.src[6] = w_k;    tp.dst[6] = wt_qk + 65536;
  tp.src[7] = w_v;    tp.dst[7] = wt_v;
  tp.src[8] = w_o;    tp.dst[8] = wt_o;
  tp.src[9] = w_down; tp.dst[9] = wt_down;
  transpose_all<<<24064, 256, 0, stream>>>(tp);

  // ---- LayerNorm ----
  ln_kernel<<<B_, 256, 0, stream>>>(x, ln_g, ln_b, xn_bf);

  // ---- merged up projections: [xul | xur] = xn @ [w_ul | w_ur] ----
  gemm8p<unsigned short, false><<<dim3(16, 32, 1), 512, 0, stream>>>(
      xn_bf, IN_, 0, wt_ulur, IN_, 0, b_ul, b_ur, 0,
      xul_bf, xur_bf, HID_, 0, 2048, nullptr, 1.f, 1.f, IN_);

  // ---- conv4 + silu ----
  conv_kernel<<<B_, 256, 0, stream>>>(xul_bf, conv_w, conv_b, xc_bf);

  // ---- merged skip|i|f from xc ----
  gemm8p<unsigned short, false><<<dim3(24, 32, 1), 512, 0, stream>>>(
      xc_bf, UP_, 0, wt_sif, UP_, 0, b_sif, nullptr, 0,
      sif_bf, sif_bf, 6144, 0, NOSPLIT, nullptr, 1.f, 1.f, UP_);

  // ---- merged q|k (blockdiag, per-head z), k scaled by 1/16 ----
  gemm8p<unsigned short, false><<<dim3(2, 32, 8), 512, 0, stream>>>(
      xc_bf, UP_, HS_, wt_qk, HS_, 512 * HS_, b_q, b_k, HS_,
      q_bf, k_bf, HID_, HS_, 256, nullptr, 1.f, 0.0625f, HS_);

  // ---- v (blockdiag from xul) ----
  gemm8p<unsigned short, false><<<dim3(1, 32, 8), 512, 0, stream>>>(
      xul_bf, UP_, HS_, wt_v, HS_, HS_ * HS_, b_v, nullptr, HS_,
      v_bf, v_bf, HID_, HS_, NOSPLIT, nullptr, 1.f, 1.f, HS_);

  // ---- o-gate linear from xul ----
  gemm8p<unsigned short, false><<<dim3(8, 32, 1), 512, 0, stream>>>(
      xul_bf, UP_, 0, wt_o, UP_, 0, b_o, nullptr, 0,
      olin_bf, olin_bf, HID_, 0, NOSPLIT, nullptr, 1.f, 1.f, UP_);

  // ---- gates -> m_t, c_t, n_t (fp32 to d_out) + nT, qT bf16 ----
  gates_kernel<<<dim3(HID_ / 64, B_ / 64, 1), 256, 0, stream>>>(
      sif_bf, k_bf, v_bf, q_bf, m_prev, c_prev, n_prev,
      m_p, c_p, n_p, nT_bf, qT_bf);

  // ---- denom: split-K x4 partial GEMMs, then reduce ----
  gemm8p<float, false><<<dim3(8, 8, 4), 512, 0, stream>>>(
      nT_bf, B_, B_ / 4, qT_bf, B_, B_ / 4, nullptr, nullptr, 0,
      part, part, HID_, HID_ * HID_, NOSPLIT, nullptr, 1.f, 1.f, B_ / 4);
  denom_reduce<<<HID_, 256, 0, stream>>>(part, denom);

  // ---- h_t, GroupNorm, fuse with skip & silu(xur) ----
  hgn_kernel<<<B_, 256, 0, stream>>>(
      c_p, olin_bf, q_bf, denom, sif_bf, xur_bf, gn_g, gn_b, h_p, pre_bf);

  // ---- down projection: split-K x2 partials, then reduce(+bias+residual) ----
  gemm8p<float, false><<<dim3(4, 32, 2), 512, 0, stream>>>(
      pre_bf, UP_, 1024, wt_down, UP_, 1024, nullptr, nullptr, 0,
      part, part, IN_, B_ * IN_, NOSPLIT, nullptr, 1.f, 1.f, 1024);
  down_reduce<<<(B_ * IN_ / 4) / 256, 256, 0, stream>>>(part, x, b_down, out_p);
}

// Round 12
// 959.410 us; speedup vs baseline: 1.0698x; 1.0108x over previous
//
#include <hip/hip_runtime.h>
#include <stdint.h>

#define B_    8192
#define IN_   1024
#define HID_  2048
#define UP_   2048
#define H_    8
#define HS_   256
#define EPS_  1e-5f

typedef __bf16 bf16x8 __attribute__((ext_vector_type(8)));
typedef float f32x4 __attribute__((ext_vector_type(4)));
typedef unsigned short u16x4 __attribute__((ext_vector_type(4)));
typedef unsigned short u16x8 __attribute__((ext_vector_type(8)));

__device__ __forceinline__ unsigned short f2bf(float f) {
  union { float f; unsigned int u; } v; v.f = f;
  unsigned int u = v.u;
  unsigned int r = (u + 0x7fffu + ((u >> 16) & 1u)) >> 16;  // RNE
  return (unsigned short)r;
}
__device__ __forceinline__ float bf2f(unsigned short h) {
  union { unsigned int u; float f; } v; v.u = ((unsigned int)h) << 16;
  return v.f;
}

// global->LDS direct load, 16B per lane (guide §5; m97/m201 pattern).
__device__ __forceinline__ void gload_lds16(const void* g, void* l) {
  auto gp = reinterpret_cast<const uint32_t __attribute__((address_space(1)))*>(
      reinterpret_cast<uintptr_t>(g));
  auto lp = reinterpret_cast<uint32_t __attribute__((address_space(3)))*>(
      reinterpret_cast<uintptr_t>(l));
  __builtin_amdgcn_global_load_lds(gp, lp, 16, 0, 0);
}

#define SB0 __builtin_amdgcn_sched_barrier(0)

// A-fragment load (4 ds_read_b128) into a named register set (rule #20).
#define PREFETCH_AF(DST, BASE, MI0)                                         \
  DST[0][0] = *(const bf16x8*)((BASE) + (aRdBase + (MI0) * 2048));          \
  DST[0][1] = *(const bf16x8*)((BASE) + ((aRdBase + (MI0) * 2048) ^ 64));   \
  DST[1][0] = *(const bf16x8*)((BASE) + (aRdBase + ((MI0) + 1) * 2048));    \
  DST[1][1] = *(const bf16x8*)((BASE) + ((aRdBase + ((MI0) + 1) * 2048) ^ 64));

#define LOAD_BFR(BASE)                                                      \
  _Pragma("unroll")                                                         \
  for (int ni = 0; ni < 4; ++ni) {                                          \
    bfr[ni][0] = *(const bf16x8*)((BASE) + (bRdBase + ni * 2048));          \
    bfr[ni][1] = *(const bf16x8*)((BASE) + ((bRdBase + ni * 2048) ^ 64));   \
  }

#define MFMA_CLUSTER(AF, Q)                                                 \
  __builtin_amdgcn_s_setprio(1);                                           \
  _Pragma("unroll")                                                         \
  for (int kq = 0; kq < 2; ++kq)                                            \
    _Pragma("unroll")                                                       \
    for (int m2 = 0; m2 < 2; ++m2)                                          \
      _Pragma("unroll")                                                     \
      for (int ni = 0; ni < 4; ++ni)                                        \
        acc[(Q) * 2 + m2][ni] = __builtin_amdgcn_mfma_f32_16x16x32_bf16(    \
            AF[m2][kq], bfr[ni][kq], acc[(Q) * 2 + m2][ni], 0, 0, 0);       \
  __builtin_amdgcn_s_setprio(0);

// ---------------------------------------------------------------------------
// 256x256 bf16 GEMM, coarse-barrier tile schedule (r11, race-fixed) +
// multi-region epilogue (r12): up to 3 column regions, each with its own
// output/bias/scale; region 2+ may read a DIFFERENT A matrix (A2, a_split)
// — per-block static choice, no sync-structure change.
// Schedule/barrier/ledger byte-identical to r11 (verified, deterministic).
// BM=BN=256, BK=64, 8 waves (2M x 4N), per-wave 128x64, acc[8][4] f32x4.
// LDS 160 KiB: A tri-buffer (T%3)*32K; B dual-buffer at +96K + (T&1)*32K.
// ---------------------------------------------------------------------------
template <typename OutT, bool HAS_ADD>
__global__ __launch_bounds__(512, 2) void gemm8p(
    const unsigned short* __restrict__ A, const unsigned short* __restrict__ A2,
    int a_split, int lda, int a_zoff,
    const unsigned short* __restrict__ W, int ldw, int w_zoff,
    const float* __restrict__ bias, const float* __restrict__ bias2,
    const float* __restrict__ bias3, int bias_zoff,
    OutT* __restrict__ C, OutT* __restrict__ C2, OutT* __restrict__ C3,
    int ldc, int ldc2, int c_zoff, int c_split, int c_split2,
    const float* __restrict__ ADD, float scale, float scale2, float scale3,
    int K)
{
  __shared__ char lds[163840];
  const int z = blockIdx.z;
  A += (size_t)z * a_zoff;
  if (A2) A2 += (size_t)z * a_zoff;
  W += (size_t)z * w_zoff;
  if (bias) bias += (size_t)z * bias_zoff;
  if (bias2) bias2 += (size_t)z * bias_zoff;
  if (bias3) bias3 += (size_t)z * bias_zoff;

  // T1: bijective XCD swizzle (m204 formula) on the flat per-z tile id.
  const int gx = gridDim.x, gy = gridDim.y;
  const int nwg = gx * gy;
  const int orig = blockIdx.y * gx + blockIdx.x;
  const int q8 = nwg >> 3, r8 = nwg & 7;
  const int xcd = orig & 7, xi = orig >> 3;
  const int wg = (xcd < r8 ? xcd * (q8 + 1) : r8 * (q8 + 1) + (xcd - r8) * q8) + xi;
  // r8: 8-tall row-group raster (bijective when 8 | gy, guard otherwise)
  int bx, by;
  if ((gy & 7) == 0) {
    const int per = gx * 8;
    const int g0 = (wg / per) * 8;
    const int rem = wg % per;
    bx = rem >> 3;
    by = g0 + (rem & 7);
  } else {
    bx = wg % gx;
    by = wg / gx;
  }

  const int t = threadIdx.x;
  const int lane = t & 63, wave = t >> 6;     // 8 waves
  const int wr = wave >> 2, wc = wave & 3;    // 2 x 4
  const int l15 = lane & 15, l4 = lane >> 4;
  const int row0 = by * 256, col0 = bx * 256;

  // staging per-lane invariants (pre-swizzled source slot)
  const int lrow = lane >> 3;                  // 0..7
  const int lslot = (lane & 7) ^ lrow;         // involution per row parity
  const size_t aLane = (size_t)lrow * lda * 2 + (size_t)lslot * 16;
  const size_t wLane = (size_t)lrow * ldw * 2 + (size_t)lslot * 16;
  const char* Abase = (const char*)((A2 && col0 >= a_split) ? A2 : A);
  const char* Wbase = (const char*)W;

  // ds_read per-lane base byte offsets within a tile (kq=0); kq=1 is ^64
  const int aRdBase = (wr * 128 + l15) * 128 + (((l4) ^ (l15 & 7)) * 16);
  const int bRdBase = (wc * 64 + l15) * 128 + (((l4) ^ (l15 & 7)) * 16);

  auto issueA = [&](int abuf, int half, int tile) {
#pragma unroll
    for (int j = 0; j < 2; ++j) {
      const int rbase = half * 128 + j * 64 + wave * 8;
      gload_lds16(Abase + (size_t)(row0 + rbase) * (lda * 2) + (size_t)tile * 128 + aLane,
                  lds + abuf * 32768 + rbase * 128 + lane * 16);
    }
  };
  auto issueB = [&](int bbuf, int half, int tile) {
#pragma unroll
    for (int j = 0; j < 2; ++j) {
      const int rbase = half * 128 + j * 64 + wave * 8;
      gload_lds16(Wbase + (size_t)(col0 + rbase) * (ldw * 2) + (size_t)tile * 128 + wLane,
                  lds + 98304 + bbuf * 32768 + rbase * 128 + lane * 16);
    }
  };

  f32x4 acc[8][4] = {};
  const int NT = K >> 6;

  bf16x8 bfr[4][2];             // B-frags for current tile (8 b128)
  bf16x8 afA[2][2], afB[2][2];  // A-frag ping-pong (4+4 b128)

  // ---- prologue: stage tile0+tile1; retire OWN tile0 DMA; barrier makes
  // ALL waves' tile0 DMA visible. NO LDS reads before this barrier. ----
  issueA(0, 0, 0); issueA(0, 1, 0);
  issueB(0, 0, 0); issueB(0, 1, 0);
  if (NT > 1) {
    issueA(1, 0, 1); issueA(1, 1, 1);
    issueB(1, 0, 1); issueB(1, 1, 1);
    asm volatile("s_waitcnt vmcnt(8)" ::: "memory");   // own tile0 loads done
  } else {
    asm volatile("s_waitcnt vmcnt(0)" ::: "memory");
  }
  __builtin_amdgcn_s_barrier();                        // tile0 globally ready
  SB0;

  for (int T = 0; T < NT; ++T) {
    const char* ldsA = lds + (T % 3) * 32768;
    const char* ldsB = lds + 98304 + (T & 1) * 32768;
    const int abufN = (T + 2) % 3;
    const int bbufN = T & 1;                   // == (T+2)&1
    // ---- body top: issue this tile's B-frags + q0/q1 A-frags (16 ds) ----
    LOAD_BFR(ldsB)
    PREFETCH_AF(afA, ldsA, 0)
    PREFETCH_AF(afB, ldsA, 2)
    SB0;
    // q0: B + afA done (16 -> 4: afB pending)
    asm volatile("s_waitcnt lgkmcnt(4)" ::: "memory"); SB0;
    MFMA_CLUSTER(afA, 0)
    PREFETCH_AF(afA, ldsA, 4)                  // q2 frags (drain under q1)
    if (T + 2 < NT) issueA(abufN, 0, T + 2);
    // q1: afB done (8 -> 4: q2 pending)
    asm volatile("s_waitcnt lgkmcnt(4)" ::: "memory"); SB0;
    MFMA_CLUSTER(afB, 1)
    __builtin_amdgcn_s_barrier();              // mid-tile: B(T) reads complete
    SB0;
    PREFETCH_AF(afB, ldsA, 6)                  // q3 frags (drain under q2)
    if (T + 2 < NT) {
      issueA(abufN, 1, T + 2);
      issueB(bbufN, 0, T + 2);                 // safe: post-mid-barrier
      issueB(bbufN, 1, T + 2);
    }
    // q2: q2 frags done (8 -> 4: q3 pending)
    asm volatile("s_waitcnt lgkmcnt(4)" ::: "memory"); SB0;
    MFMA_CLUSTER(afA, 2)
    asm volatile("s_waitcnt lgkmcnt(0)" ::: "memory"); SB0;
    MFMA_CLUSTER(afB, 3)
    // tile boundary: retire OWN T+1 DMA (keep T+2 in flight), then barrier
    if (T + 2 < NT) asm volatile("s_waitcnt vmcnt(8)" ::: "memory");
    else            asm volatile("s_waitcnt vmcnt(0)" ::: "memory");
    SB0;
    __builtin_amdgcn_s_barrier();
    SB0;
  }

  // epilogue: C/D layout col=lane&15, row=(lane>>4)*4+reg (guide §3)
  OutT* Cp; const float* bp; float sc; int cbase, myldc;
  if (col0 < c_split)        { Cp = C;  bp = bias;  sc = scale;  cbase = col0;            myldc = ldc;  }
  else if (col0 < c_split2)  { Cp = C2; bp = bias2; sc = scale2; cbase = col0 - c_split;  myldc = ldc2; }
  else                       { Cp = C3; bp = bias3; sc = scale3; cbase = col0 - c_split2; myldc = ldc2; }
#pragma unroll
  for (int mi = 0; mi < 8; ++mi) {
#pragma unroll
    for (int ni = 0; ni < 4; ++ni) {
#pragma unroll
      for (int r = 0; r < 4; ++r) {
        const int m = row0 + wr * 128 + mi * 16 + l4 * 4 + r;
        const int n = wc * 64 + ni * 16 + l15;
        float v = acc[mi][ni][r];
        if (bp) v += bp[cbase + n];
        v *= sc;
        const size_t ci = (size_t)m * myldc + (size_t)z * c_zoff + cbase + n;
        if constexpr (HAS_ADD) v += ADD[ci];
        if constexpr (sizeof(OutT) == 2) Cp[ci] = (OutT)f2bf(v);
        else Cp[ci] = v;
      }
    }
  }
}

// ---------------------------------------------------------------------------
// denom[m] = max_n | sum_z part[z][m][n] |   (split-K reduction), one block/row
// ---------------------------------------------------------------------------
__global__ __launch_bounds__(256) void denom_reduce(
    const float* __restrict__ part, float* __restrict__ denom)
{
  const int m = blockIdx.x, t = threadIdx.x;
  const size_t P = (size_t)HID_ * HID_;
  float v = 0.f;
  for (int n = t; n < HID_; n += 256) {
    const size_t o = (size_t)m * HID_ + n;
    float s = part[o] + part[P + o] + part[2 * P + o] + part[3 * P + o];
    v = fmaxf(v, fabsf(s));
  }
#pragma unroll
  for (int off = 1; off < 64; off <<= 1) v = fmaxf(v, __shfl_xor(v, off, 64));
  __shared__ float red[4];
  if ((t & 63) == 0) red[t >> 6] = v;
  __syncthreads();
  if (t == 0) denom[m] = fmaxf(fmaxf(red[0], red[1]), fmaxf(red[2], red[3]));
}

// ---------------------------------------------------------------------------
// down split-K reduce: out = part0 + part1 + bias + x
// ---------------------------------------------------------------------------
__global__ __launch_bounds__(256) void down_reduce(
    const float* __restrict__ part, const float* __restrict__ x,
    const float* __restrict__ bias, float* __restrict__ out)
{
  const size_t idx = ((size_t)blockIdx.x * 256 + threadIdx.x) * 4;
  const size_t P = (size_t)B_ * IN_;
  f32x4 a = *(const f32x4*)(part + idx);
  f32x4 b = *(const f32x4*)(part + P + idx);
  f32x4 xv = *(const f32x4*)(x + idx);
  const int j = (int)(idx & (IN_ - 1));
  f32x4 bv = *(const f32x4*)(bias + j);
  f32x4 o;
#pragma unroll
  for (int e = 0; e < 4; ++e) o[e] = a[e] + b[e] + bv[e] + xv[e];
  *(f32x4*)(out + idx) = o;
}

// ---------------------------------------------------------------------------
// Batched weight convert+transpose: ALL 10 weights in ONE dispatch.
// r12: w_o stacked into wt_sifo rows 6144-8191; q/k/v stacked per head as
// wt_qkv[z][768][256] (q rows 0-255, k 256-511, v 512-767).
// ---------------------------------------------------------------------------
struct TP {
  const float* src[10];
  unsigned short* dst[10];
};

__global__ __launch_bounds__(256) void transpose_all(TP p)
{
  __shared__ float tile[32][33];
  const int tid = blockIdx.x;
  int w, base, R, C, izoff, ozoff;
  if      (tid < 2048)  { w = 0; base = 0;     R = 1024; C = 2048; izoff = 0;     ozoff = 0; }
  else if (tid < 4096)  { w = 1; base = 2048;  R = 1024; C = 2048; izoff = 0;     ozoff = 0; }
  else if (tid < 8192)  { w = 2; base = 4096;  R = 2048; C = 2048; izoff = 0;     ozoff = 0; }
  else if (tid < 12288) { w = 3; base = 8192;  R = 2048; C = 2048; izoff = 0;     ozoff = 0; }
  else if (tid < 16384) { w = 4; base = 12288; R = 2048; C = 2048; izoff = 0;     ozoff = 0; }
  else if (tid < 16896) { w = 5; base = 16384; R = 256;  C = 256;  izoff = 65536; ozoff = 196608; }
  else if (tid < 17408) { w = 6; base = 16896; R = 256;  C = 256;  izoff = 65536; ozoff = 196608; }
  else if (tid < 17920) { w = 7; base = 17408; R = 256;  C = 256;  izoff = 65536; ozoff = 196608; }
  else if (tid < 22016) { w = 8; base = 17920; R = 2048; C = 2048; izoff = 0;     ozoff = 0; }
  else                  { w = 9; base = 22016; R = 2048; C = 1024; izoff = 0;     ozoff = 0; }
  const int local = tid - base;
  const int cx = C >> 5;
  const int tpz = cx * (R >> 5);
  const int z = local / tpz;
  const int rem = local % tpz;
  const int bx = rem % cx, by = rem / cx;
  const float* in = p.src[w] + (size_t)z * izoff;
  unsigned short* out = p.dst[w] + (size_t)z * ozoff;
  const int cb = bx * 32, rb = by * 32;
  const int tx = threadIdx.x & 31, ty = threadIdx.x >> 5;
  for (int i = ty; i < 32; i += 8)
    tile[i][tx] = in[(size_t)(rb + i) * C + cb + tx];
  __syncthreads();
  for (int i = ty; i < 32; i += 8)
    out[(size_t)(cb + i) * R + rb + tx] = f2bf(tile[tx][i]);
}

// ---------------------------------------------------------------------------
// LayerNorm over 1024 features, one block per row, write bf16.
// ---------------------------------------------------------------------------
__global__ __launch_bounds__(256) void ln_kernel(
    const float* __restrict__ x, const float* __restrict__ g,
    const float* __restrict__ b, unsigned short* __restrict__ xn)
{
  const int brow = blockIdx.x, t = threadIdx.x;
  const int lane = t & 63, wave = t >> 6;
  const float* xr = x + (size_t)brow * IN_;
  f32x4 v = *(const f32x4*)(xr + t * 4);
  float s = v[0] + v[1] + v[2] + v[3];
  float q = v[0]*v[0] + v[1]*v[1] + v[2]*v[2] + v[3]*v[3];
#pragma unroll
  for (int off = 32; off; off >>= 1) {
    s += __shfl_xor(s, off, 64);
    q += __shfl_xor(q, off, 64);
  }
  __shared__ float ss[4], sq[4];
  if (lane == 0) { ss[wave] = s; sq[wave] = q; }
  __syncthreads();
  s = ss[0] + ss[1] + ss[2] + ss[3];
  q = sq[0] + sq[1] + sq[2] + sq[3];
  const float mean = s * (1.f / IN_);
  const float var = q * (1.f / IN_) - mean * mean;
  const float rs = rsqrtf(var + EPS_);
  u16x4 o;
#pragma unroll
  for (int e = 0; e < 4; ++e) {
    const int j = t * 4 + e;
    o[e] = f2bf((v[e] - mean) * rs * g[j] + b[j]);
  }
  *(u16x4*)(xn + (size_t)brow * IN_ + t * 4) = o;
}

// ---------------------------------------------------------------------------
// Causal conv1d (k=4, left pad 3) + SiLU. One block per row.
// Vectorized: one u16x8 + one u16x4 (left-neighbor, zero for t==0). (G13)
// ---------------------------------------------------------------------------
__global__ __launch_bounds__(256) void conv_kernel(
    const unsigned short* __restrict__ xul, const float* __restrict__ cw,
    const float* __restrict__ cb, unsigned short* __restrict__ xc)
{
  const int brow = blockIdx.x, t = threadIdx.x;
  const size_t base = (size_t)brow * UP_;
  const int j0 = t * 8;
  u16x8 main8 = *(const u16x8*)(xul + base + j0);
  u16x4 prev4 = {0, 0, 0, 0};
  if (t > 0) prev4 = *(const u16x4*)(xul + base + j0 - 4);
  float xv[11];
  xv[0] = bf2f(prev4[1]);
  xv[1] = bf2f(prev4[2]);
  xv[2] = bf2f(prev4[3]);
#pragma unroll
  for (int e = 0; e < 8; ++e) xv[3 + e] = bf2f(main8[e]);
  const float w0 = cw[0], w1 = cw[1], w2 = cw[2], w3 = cw[3], bb = cb[0];
  u16x8 o;
#pragma unroll
  for (int e = 0; e < 8; ++e) {
    float sv = bb + w0 * xv[e] + w1 * xv[e + 1] + w2 * xv[e + 2] + w3 * xv[e + 3];
    o[e] = f2bf(sv / (1.f + expf(-sv)));
  }
  *(u16x8*)(xc + base + j0) = o;
}

// ---------------------------------------------------------------------------
// Gates, 64x64 tile per block: m_t,c_t,n_t fp32 + nT AND qT bf16 (LDS
// transpose; q-transpose fused).
// ---------------------------------------------------------------------------
__global__ __launch_bounds__(256) void gates_kernel(
    const unsigned short* __restrict__ sif,
    const unsigned short* __restrict__ kb, const unsigned short* __restrict__ vb,
    const unsigned short* __restrict__ qb,
    const float* __restrict__ mprev, const float* __restrict__ cprev,
    const float* __restrict__ nprev,
    float* __restrict__ mo, float* __restrict__ co, float* __restrict__ no,
    unsigned short* __restrict__ nT, unsigned short* __restrict__ qT)
{
  __shared__ unsigned short nt_t[64][72];
  __shared__ unsigned short qt_t[64][72];
  const int t = threadIdx.x;
  const int r = t >> 2, cq = t & 3;
  const int row = blockIdx.y * 64 + r;
  const int colb = blockIdx.x * 64 + cq * 16;
  const size_t hidb = (size_t)row * HID_ + colb;
  const size_t sifb = (size_t)row * 6144 + colb;
#pragma unroll
  for (int e4 = 0; e4 < 4; ++e4) {
    const int c4 = e4 * 4;
    f32x4 mp = *(const f32x4*)(mprev + hidb + c4);
    f32x4 cp = *(const f32x4*)(cprev + hidb + c4);
    f32x4 np = *(const f32x4*)(nprev + hidb + c4);
    u16x4 iv = *(const u16x4*)(sif + sifb + 2048 + c4);
    u16x4 fv = *(const u16x4*)(sif + sifb + 4096 + c4);
    u16x4 kv = *(const u16x4*)(kb + hidb + c4);
    u16x4 vv = *(const u16x4*)(vb + hidb + c4);
    u16x4 qv = *(const u16x4*)(qb + hidb + c4);
    f32x4 mo4, co4, no4;
#pragma unroll
    for (int e = 0; e < 4; ++e) {
      const float ft = bf2f(fv[e]) + mp[e];
      const float it = bf2f(iv[e]);
      const float mt = fmaxf(ft, it);
      const float ie = expf(it - mt);
      const float fe = expf(ft - mt);
      const float k = bf2f(kv[e]), v = bf2f(vv[e]);
      mo4[e] = mt;
      co4[e] = fe * cp[e] + ie * (v * k);
      no4[e] = fe * np[e] + ie * k;
      nt_t[r][cq * 16 + c4 + e] = f2bf(no4[e]);
      qt_t[r][cq * 16 + c4 + e] = qv[e];
    }
    *(f32x4*)(mo + hidb + c4) = mo4;
    *(f32x4*)(co + hidb + c4) = co4;
    *(f32x4*)(no + hidb + c4) = no4;
  }
  __syncthreads();
  const int cT = t >> 2, sq = t & 3;
  u16x8 o0, o1, p0, p1;
#pragma unroll
  for (int e = 0; e < 8; ++e) {
    o0[e] = nt_t[sq * 16 + e][cT];
    o1[e] = nt_t[sq * 16 + 8 + e][cT];
    p0[e] = qt_t[sq * 16 + e][cT];
    p1[e] = qt_t[sq * 16 + 8 + e][cT];
  }
  const size_t ob = (size_t)(blockIdx.x * 64 + cT) * B_ + blockIdx.y * 64 + sq * 16;
  *(u16x8*)(nT + ob) = o0;
  *(u16x8*)(nT + ob + 8) = o1;
  *(u16x8*)(qT + ob) = p0;
  *(u16x8*)(qT + ob + 8) = p1;
}

// ---------------------------------------------------------------------------
// h_t = o*c_t*q/denom; GroupNorm (8 groups of 256); pre = (hn+skip)*silu(xur).
// ---------------------------------------------------------------------------
__global__ __launch_bounds__(256) void hgn_kernel(
    const float* __restrict__ ct, const unsigned short* __restrict__ olin,
    const unsigned short* __restrict__ qb, const float* __restrict__ denom,
    const unsigned short* __restrict__ sif, const unsigned short* __restrict__ xurb,
    const float* __restrict__ gng, const float* __restrict__ gnb,
    float* __restrict__ ho, unsigned short* __restrict__ pre)
{
  const int brow = blockIdx.x, t = threadIdx.x;
  const size_t base = (size_t)brow * HID_ + t * 8;
  u16x8 ov = *(const u16x8*)(olin + base);
  u16x8 qv = *(const u16x8*)(qb + base);
  f32x4 c0 = *(const f32x4*)(ct + base);
  f32x4 c1 = *(const f32x4*)(ct + base + 4);
  float h[8];
  float s = 0.f, sq = 0.f;
#pragma unroll
  for (int e = 0; e < 8; ++e) {
    const float o = 1.f / (1.f + expf(-bf2f(ov[e])));
    const float cv = (e < 4) ? c0[e] : c1[e - 4];
    const float hv = o * cv * bf2f(qv[e]) / denom[t * 8 + e];
    h[e] = hv; s += hv; sq += hv * hv;
  }
#pragma unroll
  for (int e = 0; e < 8; ++e) ho[base + e] = h[e];
#pragma unroll
  for (int off = 1; off < 32; off <<= 1) {
    s += __shfl_xor(s, off, 64);
    sq += __shfl_xor(sq, off, 64);
  }
  const float mean = s * (1.f / HS_);
  const float var = sq * (1.f / HS_) - mean * mean;
  const float rs = rsqrtf(var + EPS_);
  u16x8 sv = *(const u16x8*)(sif + (size_t)brow * 6144 + t * 8);
  u16x8 xv = *(const u16x8*)(xurb + base);
  u16x8 pv;
#pragma unroll
  for (int e = 0; e < 8; ++e) {
    const int j = t * 8 + e;
    const float hn = (h[e] - mean) * rs * gng[j] + gnb[j];
    const float xr = bf2f(xv[e]);
    const float sil = xr / (1.f + expf(-xr));
    pv[e] = f2bf((hn + bf2f(sv[e])) * sil);
  }
  *(u16x8*)(pre + base) = pv;
}

// ---------------------------------------------------------------------------
extern "C" void kernel_launch(void* const* d_in, const int* in_sizes, int n_in,
                              void* d_out, int out_size, void* d_ws, size_t ws_size,
                              hipStream_t stream)
{
  const float* x      = (const float*)d_in[0];
  const float* c_prev = (const float*)d_in[2];
  const float* n_prev = (const float*)d_in[3];
  const float* m_prev = (const float*)d_in[4];
  const float* ln_g   = (const float*)d_in[5];
  const float* ln_b   = (const float*)d_in[6];
  const float* w_ul   = (const float*)d_in[7];
  const float* b_ul   = (const float*)d_in[8];
  const float* w_ur   = (const float*)d_in[9];
  const float* b_ur   = (const float*)d_in[10];
  const float* conv_w = (const float*)d_in[11];
  const float* conv_b = (const float*)d_in[12];
  const float* w_skip = (const float*)d_in[13];
  const float* b_skip = (const float*)d_in[14];
  const float* w_q    = (const float*)d_in[15];
  const float* b_q    = (const float*)d_in[16];
  const float* w_k    = (const float*)d_in[17];
  const float* b_k    = (const float*)d_in[18];
  const float* w_v    = (const float*)d_in[19];
  const float* b_v    = (const float*)d_in[20];
  const float* w_i    = (const float*)d_in[21];
  const float* b_i    = (const float*)d_in[22];
  const float* w_f    = (const float*)d_in[23];
  const float* b_f    = (const float*)d_in[24];
  const float* w_o    = (const float*)d_in[25];
  const float* b_o    = (const float*)d_in[26];
  const float* gn_g   = (const float*)d_in[27];
  const float* gn_b   = (const float*)d_in[28];
  const float* w_down = (const float*)d_in[29];
  const float* b_down = (const float*)d_in[30];

  float* out_p = (float*)d_out;                       // [B, IN]
  float* h_p = out_p + (size_t)B_ * IN_;              // [B, HID]
  float* c_p = h_p + (size_t)B_ * HID_;
  float* n_p = c_p + (size_t)B_ * HID_;
  float* m_p = n_p + (size_t)B_ * HID_;

  char* ws = (char*)d_ws;
  size_t off = 0;
  auto alloc = [&](size_t n) -> void* {
    void* p = ws + off;
    off += (n + 255) & ~(size_t)255;
    return p;
  };

  const size_t BH2 = (size_t)B_ * HID_ * 2;

  unsigned short* xn_bf   = (unsigned short*)alloc((size_t)B_ * IN_ * 2);
  unsigned short* xul_bf  = (unsigned short*)alloc(BH2);
  unsigned short* xur_bf  = (unsigned short*)alloc(BH2);
  unsigned short* xc_bf   = (unsigned short*)alloc(BH2);
  unsigned short* sif_bf  = (unsigned short*)alloc((size_t)B_ * 6144 * 2);
  unsigned short* q_bf    = (unsigned short*)alloc(BH2);
  unsigned short* k_bf    = (unsigned short*)alloc(BH2);
  unsigned short* v_bf    = (unsigned short*)alloc(BH2);
  unsigned short* olin_bf = (unsigned short*)alloc(BH2);
  unsigned short* qT_bf   = (unsigned short*)alloc(BH2);
  unsigned short* nT_bf   = (unsigned short*)alloc(BH2);
  unsigned short* pre_bf  = (unsigned short*)alloc(BH2);
  float* denom = (float*)alloc(HID_ * sizeof(float));
  float* part  = (float*)alloc((size_t)4 * HID_ * HID_ * sizeof(float));
  float* b_sif = (float*)alloc(6144 * sizeof(float));
  unsigned short* wt_ulur = (unsigned short*)alloc((size_t)4096 * IN_ * 2);
  unsigned short* wt_sifo = (unsigned short*)alloc((size_t)8192 * UP_ * 2);
  unsigned short* wt_qkv  = (unsigned short*)alloc((size_t)H_ * 768 * HS_ * 2);
  unsigned short* wt_down = (unsigned short*)alloc((size_t)HID_ * IN_ * 2);

  if (off > ws_size) return;  // fail loudly (poisoned output) rather than OOB

  const int NS = 1 << 30;  // "no split" sentinel

  // ---- stacked biases (d2d async copies, graph-capture safe) ----
  hipMemcpyAsync(b_sif, b_skip, 2048 * 4, hipMemcpyDeviceToDevice, stream);
  hipMemcpyAsync(b_sif + 2048, b_i, 2048 * 4, hipMemcpyDeviceToDevice, stream);
  hipMemcpyAsync(b_sif + 4096, b_f, 2048 * 4, hipMemcpyDeviceToDevice, stream);

  // ---- ALL weight transposes in one dispatch ----
  TP tp;
  tp.src[0] = w_ul;   tp.dst[0] = wt_ulur;
  tp.src[1] = w_ur;   tp.dst[1] = wt_ulur + (size_t)2048 * 1024;
  tp.src[2] = w_skip; tp.dst[2] = wt_sifo;
  tp.src[3] = w_i;    tp.dst[3] = wt_sifo + (size_t)2048 * 2048;
  tp.src[4] = w_f;    tp.dst[4] = wt_sifo + (size_t)4096 * 2048;
  tp.src[5] = w_q;    tp.dst[5] = wt_qkv;
  tp.src[6] = w_k;    tp.dst[6] = wt_qkv + 65536;
  tp.src[7] = w_v;    tp.dst[7] = wt_qkv + 131072;
  tp.src[8] = w_o;    tp.dst[8] = wt_sifo + (size_t)6144 * 2048;
  tp.src[9] = w_down; tp.dst[9] = wt_down;
  transpose_all<<<24064, 256, 0, stream>>>(tp);

  // ---- LayerNorm ----
  ln_kernel<<<B_, 256, 0, stream>>>(x, ln_g, ln_b, xn_bf);

  // ---- merged up projections: [xul | xur] = xn @ [w_ul | w_ur] ----
  gemm8p<unsigned short, false><<<dim3(16, 32, 1), 512, 0, stream>>>(
      xn_bf, nullptr, NS, IN_, 0, wt_ulur, IN_, 0,
      b_ul, b_ur, nullptr, 0,
      xul_bf, xur_bf, nullptr, HID_, HID_, 0, 2048, NS,
      nullptr, 1.f, 1.f, 1.f, IN_);

  // ---- conv4 + silu ----
  conv_kernel<<<B_, 256, 0, stream>>>(xul_bf, conv_w, conv_b, xc_bf);

  // ---- merged skip|i|f (from xc) + o-gate (from xul): N=8192 ----
  gemm8p<unsigned short, false><<<dim3(32, 32, 1), 512, 0, stream>>>(
      xc_bf, xul_bf, 6144, UP_, 0, wt_sifo, UP_, 0,
      b_sif, b_o, nullptr, 0,
      sif_bf, olin_bf, nullptr, 6144, HID_, 0, 6144, NS,
      nullptr, 1.f, 1.f, 1.f, UP_);

  // ---- merged q|k|v (blockdiag per-head z): q,k from xc, v from xul ----
  gemm8p<unsigned short, false><<<dim3(3, 32, 8), 512, 0, stream>>>(
      xc_bf, xul_bf, 512, UP_, HS_, wt_qkv, HS_, 768 * HS_,
      b_q, b_k, b_v, HS_,
      q_bf, k_bf, v_bf, HID_, HID_, HS_, 256, 512,
      nullptr, 1.f, 0.0625f, 1.f, HS_);

  // ---- gates -> m_t, c_t, n_t (fp32 to d_out) + nT, qT bf16 ----
  gates_kernel<<<dim3(HID_ / 64, B_ / 64, 1), 256, 0, stream>>>(
      sif_bf, k_bf, v_bf, q_bf, m_prev, c_prev, n_prev,
      m_p, c_p, n_p, nT_bf, qT_bf);

  // ---- denom: split-K x4 partial GEMMs, then reduce ----
  gemm8p<float, false><<<dim3(8, 8, 4), 512, 0, stream>>>(
      nT_bf, nullptr, NS, B_, B_ / 4, qT_bf, B_, B_ / 4,
      nullptr, nullptr, nullptr, 0,
      part, part, nullptr, HID_, HID_, HID_ * HID_, NS, NS,
      nullptr, 1.f, 1.f, 1.f, B_ / 4);
  denom_reduce<<<HID_, 256, 0, stream>>>(part, denom);

  // ---- h_t, GroupNorm, fuse with skip & silu(xur) ----
  hgn_kernel<<<B_, 256, 0, stream>>>(
      c_p, olin_bf, q_bf, denom, sif_bf, xur_bf, gn_g, gn_b, h_p, pre_bf);

  // ---- down projection: split-K x2 partials, then reduce(+bias+residual) ----
  gemm8p<float, false><<<dim3(4, 32, 2), 512, 0, stream>>>(
      pre_bf, nullptr, NS, UP_, 1024, wt_down, UP_, 1024,
      nullptr, nullptr, nullptr, 0,
      part, part, nullptr, IN_, IN_, B_ * IN_, NS, NS,
      nullptr, 1.f, 1.f, 1.f, 1024);
  down_reduce<<<(B_ * IN_ / 4) / 256, 256, 0, stream>>>(part, x, b_down, out_p);
}